// Round 8
// baseline (537.813 us; speedup 1.0000x reference)
//
#include <hip/hip_runtime.h>
#include <hip/hip_bf16.h>
#include <math.h>

// ---------------- problem constants ----------------
static constexpr int NBATCH = 4;
static constexpr int NPTS   = 4096;
static constexpr int BN     = NBATCH * NPTS;   // 16384
static constexpr int KNN    = 20;
static constexpr float BN_EPS = 1e-5f;
static constexpr float SLOPE  = 0.2f;
static constexpr int DF = 512, DOUT = 256;

#define FINF __builtin_huge_valf()

typedef short bf16x8 __attribute__((ext_vector_type(8)));
typedef float f32x4  __attribute__((ext_vector_type(4)));

// ---------------- workspace layout (bytes) ----------------
static constexpr size_t OFF_H0     = 0;                    // 4 MB: VMM0
static constexpr size_t OFF_IDX0   = 4194304;              // 1.25 MB
static constexpr size_t OFF_IDX1   = 5505024;              // 1.25 MB
static constexpr size_t OFF_D2     = 6815744;              // 64 KB
static constexpr size_t OFF_GATE   = 6881280;              // 64 KB
static constexpr size_t OFF_ALPHA  = 6946816;              // 64 KB
static constexpr size_t OFF_SS0    = 7012352;
static constexpr size_t OFF_SS1    = 7012864;
static constexpr size_t OFF_STATS0 = 7014912;
static constexpr size_t OFF_STATS1 = 7015424;
static constexpr size_t OFF_POOLED = 7017472;              // -> 7,025,664
static constexpr size_t ZERO_OFF   = OFF_STATS0;
static constexpr size_t ZERO_BYTES = 7025664 - 7014912;
static constexpr size_t OFF_P1     = 7025664;              // 16 MB (gemm_pq1 out)
static constexpr size_t OFF_PDU    = OFF_P1;               // S=8: 10.49 MB (dead before P1)
static constexpr size_t OFF_WQK    = 23802880;             // 512*128*2 = 131,072
static constexpr size_t OFF_WFK    = 23933952;             // 512*512*2 = 524,288 -> 24,458,240
static constexpr size_t OFF_Q1     = 27997184;             // 16 MB
static constexpr size_t OFF_U0     = OFF_Q1;               // 1 MB (dead before P0)
static constexpr size_t OFF_V0     = OFF_Q1 + 1048576;     // 1 MB
static constexpr size_t OFF_P0     = OFF_Q1;               // 4 MB
static constexpr size_t OFF_Q0     = OFF_Q1 + 4194304;     // 4 MB
static constexpr size_t OFF_H1     = 44774400;             // 16 MB: VMM1 then AB1 (in place)
static constexpr size_t OFF_AB     = 61551616;             // 4 MB -> 65,745,920

// ---------------- helpers ----------------
__device__ inline unsigned short f2bf_rne(float x) {
  unsigned int u = __float_as_uint(x);
  unsigned int lsb = (u >> 16) & 1u;
  u += 0x7fffu + lsb;
  return (unsigned short)(u >> 16);
}
__device__ inline float bf2f(unsigned short s) {
  return __uint_as_float((unsigned int)s << 16);
}
__device__ inline unsigned umn(unsigned a, unsigned b) { return a < b ? a : b; }
__device__ inline unsigned umx(unsigned a, unsigned b) { return a > b ? a : b; }
// sorted-insert slot update: min(max(v,lo),hi) -> ISel emits v_med3_u32.
// Identity when v >= hi -> insert runs unconditionally.

// ---------------- d2 = sum(x*x), D=3 ----------------
__global__ __launch_bounds__(256) void d2x_kernel(const float* __restrict__ x,
                                                  float* __restrict__ d2) {
  int n = blockIdx.x * 256 + threadIdx.x;
  const float* r = x + (size_t)n * 3;
  d2[n] = r[0] * r[0] + r[1] * r[1] + r[2] * r[2];
}

// ---------------- layer-0 packing: U=[A,B,A,B,0..] (queries), V=[A,A,B,B,0..] ----
__global__ __launch_bounds__(256) void usplit0_kernel(
    const float* __restrict__ x, unsigned short* __restrict__ U0,
    unsigned short* __restrict__ V0) {
  int n = blockIdx.x * 256 + threadIdx.x;
  float v0 = x[(size_t)n * 3], v1 = x[(size_t)n * 3 + 1], v2 = x[(size_t)n * 3 + 2];
  unsigned short A0 = f2bf_rne(v0), A1 = f2bf_rne(v1), A2 = f2bf_rne(v2);
  unsigned short B0 = f2bf_rne(v0 - bf2f(A0));
  unsigned short B1 = f2bf_rne(v1 - bf2f(A1));
  unsigned short B2 = f2bf_rne(v2 - bf2f(A2));
  ushort4 z = make_ushort4(0, 0, 0, 0);
  unsigned short* up = U0 + ((size_t)n << 5);
  ((ushort4*)up)[0] = make_ushort4(A0, A1, A2, B0);
  ((ushort4*)up)[1] = make_ushort4(B1, B2, A0, A1);
  ((ushort4*)up)[2] = make_ushort4(A2, B0, B1, B2);
  ((ushort4*)up)[3] = z; ((ushort4*)up)[4] = z; ((ushort4*)up)[5] = z;
  ((ushort4*)up)[6] = z; ((ushort4*)up)[7] = z;
  unsigned short* vp = V0 + ((size_t)n << 5);
  ((ushort4*)vp)[0] = make_ushort4(A0, A1, A2, A0);
  ((ushort4*)vp)[1] = make_ushort4(A1, A2, B0, B1);
  ((ushort4*)vp)[2] = make_ushort4(B2, B0, B1, B2);
  ((ushort4*)vp)[3] = z; ((ushort4*)vp)[4] = z; ((ushort4*)vp)[5] = z;
  ((ushort4*)vp)[6] = z; ((ushort4*)vp)[7] = z;
}

// ---------------- unified MFMA KNN with in-register med3 selection ----------------
template<int KW, int CST, int S>
__global__ __launch_bounds__(256, 4) void knn_mfsel_kernel(
    const unsigned short* __restrict__ cab,
    const unsigned short* __restrict__ qab,
    const float* __restrict__ d2,
    unsigned* __restrict__ pdu) {
  constexpr int CS = NPTS / S, NCH = CS / 32;
  __shared__ __align__(16) unsigned short cbuf[2][32 * CST];
  __shared__ __align__(16) float cd2b[2][32];

  int bid = blockIdx.x;
  int s   = bid & (S - 1);
  int qb  = bid / S;
  int b   = qb >> 6;
  int qloc = (qb & 63) * 64;
  int wv = threadIdx.x >> 6, lane = threadIdx.x & 63;
  int l15 = lane & 15, lg = lane >> 4;
  int qg = b * NPTS + qloc + wv * 16 + l15;

  bf16x8 af[KW / 32];
#pragma unroll
  for (int kk = 0; kk < KW / 32; ++kk)
    af[kk] = *(const bf16x8*)(qab + (size_t)qg * KW + kk * 32 + lg * 8);
  float d2q = d2[qg];

  unsigned bd[KNN];
#pragma unroll
  for (int k = 0; k < KNN; ++k) bd[k] = 0xFFFFFFFFu;

  int scand = threadIdx.x >> 3, sseg = threadIdx.x & 7;
  const unsigned short* sbase = cab + ((size_t)(b * NPTS + s * CS)) * KW;
  const float* d2base = d2 + b * NPTS + s * CS;

  bf16x8 r0, r1;
  ushort4 r2;
  float rd2 = 0.f;

  if constexpr (KW == 128) {
    const unsigned short* src = sbase + (size_t)scand * KW + sseg * 16;
    r0 = *(const bf16x8*)src;
    r1 = *(const bf16x8*)(src + 8);
    *(bf16x8*)&cbuf[0][scand * CST + sseg * 16]     = r0;
    *(bf16x8*)&cbuf[0][scand * CST + sseg * 16 + 8] = r1;
  } else {
    r2 = *(const ushort4*)(sbase + (size_t)scand * KW + sseg * 4);
    *(ushort4*)&cbuf[0][scand * CST + sseg * 4] = r2;
  }
  if (threadIdx.x < 32) cd2b[0][threadIdx.x] = d2base[threadIdx.x];
  __syncthreads();

#pragma unroll 1
  for (int ch = 0; ch < NCH; ++ch) {
    int cur = ch & 1;
    if (ch < NCH - 1) {
      if constexpr (KW == 128) {
        const unsigned short* src = sbase + (size_t)(32 * (ch + 1) + scand) * KW + sseg * 16;
        r0 = *(const bf16x8*)src;
        r1 = *(const bf16x8*)(src + 8);
      } else {
        r2 = *(const ushort4*)(sbase + (size_t)(32 * (ch + 1) + scand) * KW + sseg * 4);
      }
      if (threadIdx.x < 32) rd2 = d2base[32 * (ch + 1) + threadIdx.x];
    }

    f32x4 acc0 = (f32x4){0.f, 0.f, 0.f, 0.f};
    f32x4 acc1 = (f32x4){0.f, 0.f, 0.f, 0.f};
    if constexpr (KW == 128) {
#pragma unroll
      for (int j = 0; j < 4; ++j) {
        int koff = j * 32 + lg * 8;
        bf16x8 a0 = *(const bf16x8*)&cbuf[cur][l15 * CST + koff];
        bf16x8 a1 = *(const bf16x8*)&cbuf[cur][(16 + l15) * CST + koff];
        acc0 = __builtin_amdgcn_mfma_f32_16x16x32_bf16(a0, af[j], acc0, 0, 0, 0);
        acc0 = __builtin_amdgcn_mfma_f32_16x16x32_bf16(a0, af[(j + 2) & 3], acc0, 0, 0, 0);
        acc1 = __builtin_amdgcn_mfma_f32_16x16x32_bf16(a1, af[j], acc1, 0, 0, 0);
        acc1 = __builtin_amdgcn_mfma_f32_16x16x32_bf16(a1, af[(j + 2) & 3], acc1, 0, 0, 0);
      }
    } else {
      bf16x8 a0 = *(const bf16x8*)&cbuf[cur][l15 * CST + lg * 8];
      bf16x8 a1 = *(const bf16x8*)&cbuf[cur][(16 + l15) * CST + lg * 8];
      acc0 = __builtin_amdgcn_mfma_f32_16x16x32_bf16(a0, af[0], acc0, 0, 0, 0);
      acc1 = __builtin_amdgcn_mfma_f32_16x16x32_bf16(a1, af[0], acc1, 0, 0, 0);
    }

    int cb = s * CS + ch * 32;
#pragma unroll
    for (int t = 0; t < 2; ++t) {
      f32x4 cd4 = *(const f32x4*)&cd2b[cur][t * 16 + lg * 4];
      f32x4 ac = t ? acc1 : acc0;
#pragma unroll
      for (int r = 0; r < 4; ++r) {
        float dist = fmaxf(fmaf(-2.f, ac[r], d2q + cd4[r]), 0.f);
        unsigned key = (__float_as_uint(dist) & 0xFFFFF000u)
                     | (unsigned)(cb + t * 16 + lg * 4 + r);
#pragma unroll
        for (int t_ = KNN - 1; t_ >= 1; --t_) bd[t_] = umn(umx(key, bd[t_ - 1]), bd[t_]);
        bd[0] = umn(bd[0], key);
      }
    }

    if (ch < NCH - 1) {
      if constexpr (KW == 128) {
        *(bf16x8*)&cbuf[cur ^ 1][scand * CST + sseg * 16]     = r0;
        *(bf16x8*)&cbuf[cur ^ 1][scand * CST + sseg * 16 + 8] = r1;
      } else {
        *(ushort4*)&cbuf[cur ^ 1][scand * CST + sseg * 4] = r2;
      }
      if (threadIdx.x < 32) cd2b[cur ^ 1][threadIdx.x] = rd2;
    }
    __syncthreads();
  }

  // merge 4 per-lane sorted lists via shuffles into lg==0 lanes (exact union)
#pragma unroll 1
  for (int li = 1; li < 4; ++li) {
#pragma unroll 1
    for (int k = 0; k < KNN; ++k) {
      unsigned v = __shfl(bd[k], l15 + li * 16, 64);
      if (lg == 0 && v < bd[KNN - 1]) {
#pragma unroll
        for (int t_ = KNN - 1; t_ >= 1; --t_) bd[t_] = umn(umx(v, bd[t_ - 1]), bd[t_]);
        bd[0] = umn(bd[0], v);
      }
    }
  }
  if (lg == 0) {
    unsigned* dst = pdu + ((size_t)(b * NPTS + qloc + wv * 16 + l15) * S + s) * KNN;
#pragma unroll
    for (int k = 0; k < KNN; ++k) dst[k] = bd[k];
  }
}

// ---------------- merge S sorted packed-key lists -> idx ----------------
template<int S>
__global__ __launch_bounds__(256) void knn_mergek_kernel(
    const unsigned* __restrict__ pdu, int* __restrict__ idx) {
  int n = blockIdx.x * 256 + threadIdx.x;
  const unsigned* l0 = pdu + (size_t)n * S * KNN;
  unsigned bd[KNN];
#pragma unroll
  for (int k = 0; k < KNN; ++k) bd[k] = l0[k];
#pragma unroll 1
  for (int s = 1; s < S; ++s) {
#pragma unroll 1
    for (int k = 0; k < KNN; ++k) {
      unsigned v = l0[s * KNN + k];
      if (!(v < bd[KNN - 1])) break;
#pragma unroll
      for (int t_ = KNN - 1; t_ >= 1; --t_) bd[t_] = umn(umx(v, bd[t_ - 1]), bd[t_]);
      bd[0] = umn(bd[0], v);
    }
  }
#pragma unroll
  for (int k = 0; k < KNN; ++k) idx[(size_t)n * KNN + k] = (int)(bd[k] & 0xFFFu);
}

// ---------------- EdgeConv0: P,Q projections (D=3) ----------------
__global__ __launch_bounds__(256) void pq0_kernel(
    const float* __restrict__ x,
    const float* __restrict__ Wt, const float* __restrict__ bt,
    const float* __restrict__ Wp, const float* __restrict__ bp,
    float* __restrict__ P0, float* __restrict__ Q0) {
  int t = blockIdx.x * 256 + threadIdx.x;
  int c = t & 63, n = t >> 6;
  const float* xr = x + (size_t)n * 3;
  float x0 = xr[0], x1 = xr[1], x2 = xr[2];
  float wt0 = Wt[0 * 64 + c], wt1 = Wt[1 * 64 + c], wt2 = Wt[2 * 64 + c];
  float wp0 = Wp[0 * 64 + c], wp1 = Wp[1 * 64 + c], wp2 = Wp[2 * 64 + c];
  P0[t] = x0 * wt0 + x1 * wt1 + x2 * wt2 + bt[c] + bp[c];
  Q0[t] = x0 * (wp0 - wt0) + x1 * (wp1 - wt1) + x2 * (wp2 - wt2);
}

// ---------------- fused BN gather: stats + per-(n,c) bf16 vmax/vmin ----------------
template<int C, int PB>
__global__ __launch_bounds__(256) void bn_gather_kernel(
    const float* __restrict__ P, const float* __restrict__ Q,
    const int* __restrict__ idx, float* __restrict__ stats,
    unsigned* __restrict__ vmm) {
  constexpr int G = 256 / C;
  int c = threadIdx.x % C;
  int g = threadIdx.x / C;
  int p0 = blockIdx.x * PB;
  float sum = 0.f, sq = 0.f;
  for (int p = g; p < PB; p += G) {
    int n = p0 + p;
    int b = n >> 12;
    float pc = P[(size_t)n * C + c];
    const int* id = idx + (size_t)n * KNN;
    float vmax = -FINF, vmin = FINF;
#pragma unroll
    for (int k = 0; k < KNN; ++k) {
      int j = id[k];
      float v = pc + Q[((size_t)(b << 12) + j) * C + c];
      sum += v; sq += v * v;
      vmax = fmaxf(vmax, v); vmin = fminf(vmin, v);
    }
    vmm[(size_t)n * C + c] = ((unsigned)f2bf_rne(vmax) << 16) | f2bf_rne(vmin);
  }
  if constexpr (G > 1) {
    __shared__ float ls[2][256];
    ls[0][threadIdx.x] = sum; ls[1][threadIdx.x] = sq;
    __syncthreads();
    if (g == 0) {
#pragma unroll
      for (int gg = 1; gg < G; ++gg) { sum += ls[0][gg * C + c]; sq += ls[1][gg * C + c]; }
      atomicAdd(&stats[c], sum); atomicAdd(&stats[C + c], sq);
    }
  } else {
    atomicAdd(&stats[c], sum); atomicAdd(&stats[C + c], sq);
  }
}

template<int C>
__global__ void bn_final_kernel(const float* __restrict__ stats,
                                const float* __restrict__ gamma,
                                const float* __restrict__ beta,
                                float* __restrict__ ss) {
  int c = threadIdx.x;
  if (c < C) {
    const float cnt = (float)((size_t)BN * KNN);
    float mu  = stats[c] / cnt;
    float var = stats[C + c] / cnt - mu * mu;
    float sc  = gamma[c] * rsqrtf(var + BN_EPS);
    ss[c] = sc;
    ss[C + c] = beta[c] - mu * sc;
  }
}

// ---------------- apply0: affine+lrelu from vmm0 -> AB split + D2 ----------------
__global__ __launch_bounds__(256) void apply0_kernel(
    const unsigned* __restrict__ vmm, const float* __restrict__ ss,
    unsigned short* __restrict__ ab, float* __restrict__ d2) {
  int wv = threadIdx.x >> 6, lane = threadIdx.x & 63;
  int n = blockIdx.x * 4 + wv;
  unsigned pk = vmm[(size_t)n * 64 + lane];
  float sc = ss[lane], sh = ss[64 + lane];
  float vmax = bf2f((unsigned short)(pk >> 16));
  float vmin = bf2f((unsigned short)(pk & 0xFFFFu));
  float m = (sc >= 0.f) ? vmax : vmin;
  float y = fmaf(m, sc, sh);
  y = (y >= 0.f) ? y : SLOPE * y;
  unsigned short a = f2bf_rne(y);
  unsigned short b = f2bf_rne(y - bf2f(a));
  ab[(size_t)n * 128 + lane] = a;
  ab[(size_t)n * 128 + 64 + lane] = b;
  float s = y * y;
#pragma unroll
  for (int off = 32; off >= 1; off >>= 1) s += __shfl_down(s, off);
  if (lane == 0) d2[n] = s;
}

// ---------------- weight prep: Wqk[512 outcol][128 k] = split([Wt | Wp-Wt]) ------
__global__ __launch_bounds__(256) void wprep1_kernel(
    const float* __restrict__ Wt, const float* __restrict__ Wp,
    unsigned short* __restrict__ wqk) {
  int t = blockIdx.x * 256 + threadIdx.x;   // over 512*64
  int o = t >> 6, k = t & 63;
  float w;
  if (o < 256) w = Wt[(size_t)k * 256 + o];
  else { int oo = o - 256; w = Wp[(size_t)k * 256 + oo] - Wt[(size_t)k * 256 + oo]; }
  unsigned short a = f2bf_rne(w);
  wqk[(size_t)o * 128 + k]      = a;
  wqk[(size_t)o * 128 + 64 + k] = f2bf_rne(w - bf2f(a));
}

// ---------------- weight prep: Wfk[512 outcol][512 k] = split(Wf) ----------------
__global__ __launch_bounds__(256) void wprepf_kernel(
    const float* __restrict__ Wf, unsigned short* __restrict__ wfk) {
  int t = blockIdx.x * 256 + threadIdx.x;   // over 512*256
  int o = t >> 8, k = t & 255;
  float w = Wf[(size_t)k * 512 + o];
  unsigned short a = f2bf_rne(w);
  wfk[(size_t)o * 512 + k]       = a;
  wfk[(size_t)o * 512 + 256 + k] = f2bf_rne(w - bf2f(a));
}

// ---------------- gemm_pq1: [BN,128sp]@[128sp,512] -> P1|Q1, exact split, bias ----
// grid = (BN/64)*2; block 4 waves; wave covers 64 cols.
__global__ __launch_bounds__(256, 2) void gemm_pq1_kernel(
    const unsigned short* __restrict__ ab, const unsigned short* __restrict__ wqk,
    const float* __restrict__ bt, const float* __restrict__ bp,
    float* __restrict__ P1, float* __restrict__ Q1) {
  __shared__ __align__(16) unsigned short As[64 * 136];
  int cb = blockIdx.x & 1;
  int rb = blockIdx.x >> 1;
  int wv = threadIdx.x >> 6, lane = threadIdx.x & 63;
  int l15 = lane & 15, lg = lane >> 4;
  {
    int row = threadIdx.x >> 2, seg = threadIdx.x & 3;
    const unsigned short* src = ab + ((size_t)(rb * 64 + row)) * 128 + seg * 32;
    *(bf16x8*)&As[row * 136 + seg * 32]      = *(const bf16x8*)(src);
    *(bf16x8*)&As[row * 136 + seg * 32 + 8]  = *(const bf16x8*)(src + 8);
    *(bf16x8*)&As[row * 136 + seg * 32 + 16] = *(const bf16x8*)(src + 16);
    *(bf16x8*)&As[row * 136 + seg * 32 + 24] = *(const bf16x8*)(src + 24);
  }
  __syncthreads();
  int wcol = cb * 256 + wv * 64;
  f32x4 acc[4][4];
#pragma unroll
  for (int m = 0; m < 4; ++m)
#pragma unroll
    for (int n = 0; n < 4; ++n) acc[m][n] = (f32x4){0.f, 0.f, 0.f, 0.f};
#pragma unroll
  for (int kk = 0; kk < 4; ++kk) {
    int k0 = kk * 32 + lg * 8;
    int k1 = ((kk + 2) & 3) * 32 + lg * 8;
    bf16x8 am[4], b0[4], b1[4];
#pragma unroll
    for (int m = 0; m < 4; ++m)
      am[m] = *(const bf16x8*)&As[(m * 16 + l15) * 136 + k0];
#pragma unroll
    for (int n = 0; n < 4; ++n) {
      const unsigned short* wr = wqk + (size_t)(wcol + n * 16 + l15) * 128;
      b0[n] = *(const bf16x8*)(wr + k0);
      b1[n] = *(const bf16x8*)(wr + k1);
    }
#pragma unroll
    for (int m = 0; m < 4; ++m)
#pragma unroll
      for (int n = 0; n < 4; ++n) {
        acc[m][n] = __builtin_amdgcn_mfma_f32_16x16x32_bf16(am[m], b0[n], acc[m][n], 0, 0, 0);
        acc[m][n] = __builtin_amdgcn_mfma_f32_16x16x32_bf16(am[m], b1[n], acc[m][n], 0, 0, 0);
      }
  }
  // epilogue: D[row=m*16+lg*4+r][col=wcol+n*16+l15]
#pragma unroll
  for (int n = 0; n < 4; ++n) {
    int col = wcol + n * 16 + l15;
    bool isP = col < 256;
    float bias = isP ? (bt[col] + bp[col]) : 0.f;
    float* dst = isP ? (P1 + col) : (Q1 + (col - 256));
#pragma unroll
    for (int m = 0; m < 4; ++m)
#pragma unroll
      for (int r = 0; r < 4; ++r) {
        int row = rb * 64 + m * 16 + lg * 4 + r;
        dst[(size_t)row * 256] = acc[m][n][r] + bias;
      }
  }
}

// ---------------- apply1: vmm1 -> AB1 (in place) + gate ----------------
__global__ __launch_bounds__(256) void apply1_kernel(
    const unsigned* __restrict__ vmm, const float* __restrict__ ss,
    const float* __restrict__ Wg, const float* __restrict__ bg,
    unsigned short* __restrict__ ab1, float* __restrict__ gate) {
  int wv = threadIdx.x >> 6, lane = threadIdx.x & 63;
  int n = blockIdx.x * 4 + wv;
  unsigned pk[4];
#pragma unroll
  for (int i = 0; i < 4; ++i) pk[i] = vmm[(size_t)n * 256 + lane + 64 * i];  // all reads first
  float gsum = 0.f;
  unsigned short Aa[4], Bb[4];
#pragma unroll
  for (int i = 0; i < 4; ++i) {
    int c = lane + 64 * i;
    float sc = ss[c], sh = ss[256 + c];
    float vmax = bf2f((unsigned short)(pk[i] >> 16));
    float vmin = bf2f((unsigned short)(pk[i] & 0xFFFFu));
    float m = (sc >= 0.f) ? vmax : vmin;
    float y = fmaf(m, sc, sh);
    y = (y >= 0.f) ? y : SLOPE * y;
    Aa[i] = f2bf_rne(y);
    Bb[i] = f2bf_rne(y - bf2f(Aa[i]));
    gsum += y * Wg[c];
  }
#pragma unroll
  for (int i = 0; i < 4; ++i) {
    ab1[(size_t)n * 512 + lane + 64 * i]       = Aa[i];
    ab1[(size_t)n * 512 + 256 + lane + 64 * i] = Bb[i];
  }
#pragma unroll
  for (int off = 32; off >= 1; off >>= 1) gsum += __shfl_down(gsum, off);
  if (lane == 0) gate[n] = fmaxf(gsum + bg[0], 0.f);
}

// ---------------- softmax over N per batch ----------------
__global__ void softmax_kernel(const float* __restrict__ gate,
                               float* __restrict__ alpha) {
  __shared__ float red[256];
  int b = blockIdx.x;
  const float* g = gate + (size_t)b * NPTS;
  float* a = alpha + (size_t)b * NPTS;
  float m = -FINF;
  for (int i = threadIdx.x; i < NPTS; i += 256) m = fmaxf(m, g[i]);
  red[threadIdx.x] = m; __syncthreads();
  for (int st = 128; st >= 1; st >>= 1) {
    if (threadIdx.x < st) red[threadIdx.x] = fmaxf(red[threadIdx.x], red[threadIdx.x + st]);
    __syncthreads();
  }
  m = red[0]; __syncthreads();
  float s = 0.f;
  for (int i = threadIdx.x; i < NPTS; i += 256) s += expf(g[i] - m);
  red[threadIdx.x] = s; __syncthreads();
  for (int st = 128; st >= 1; st >>= 1) {
    if (threadIdx.x < st) red[threadIdx.x] += red[threadIdx.x + st];
    __syncthreads();
  }
  float inv = 1.f / red[0];
  for (int i = threadIdx.x; i < NPTS; i += 256) a[i] = expf(g[i] - m) * inv;
}

// ---------------- gemm_fp: feat GEMM (split, K=512) + relu + alpha-pool ----------
// grid = (BN/64)*2; block 4 waves; wave cols 64.
__global__ __launch_bounds__(256, 2) void gemm_fp_kernel(
    const unsigned short* __restrict__ ab1, const unsigned short* __restrict__ wfk,
    const float* __restrict__ bf, const float* __restrict__ alpha,
    float* __restrict__ pooled) {
  __shared__ __align__(16) unsigned short As[2][64 * 136];
  int cb = blockIdx.x & 1;
  int rb = blockIdx.x >> 1;
  int wv = threadIdx.x >> 6, lane = threadIdx.x & 63;
  int l15 = lane & 15, lg = lane >> 4;
  int wcol = cb * 256 + wv * 64;
  int rowbase = rb * 64;
  f32x4 acc[4][4];
#pragma unroll
  for (int m = 0; m < 4; ++m)
#pragma unroll
    for (int n = 0; n < 4; ++n) acc[m][n] = (f32x4){0.f, 0.f, 0.f, 0.f};

#pragma unroll 1
  for (int kc = 0; kc < 2; ++kc) {
    __syncthreads();
    {
      int row = threadIdx.x >> 2, seg = threadIdx.x & 3;
      const unsigned short* s0 = ab1 + ((size_t)(rowbase + row)) * 512 + kc * 128 + seg * 32;
      const unsigned short* s1 = s0 + 256;
#pragma unroll
      for (int u = 0; u < 4; ++u) {
        *(bf16x8*)&As[0][row * 136 + seg * 32 + u * 8] = *(const bf16x8*)(s0 + u * 8);
        *(bf16x8*)&As[1][row * 136 + seg * 32 + u * 8] = *(const bf16x8*)(s1 + u * 8);
      }
    }
    __syncthreads();
#pragma unroll
    for (int h = 0; h < 2; ++h) {
#pragma unroll
      for (int kk = 0; kk < 4; ++kk) {
        int s  = kc * 4 + h * 8 + kk;      // absolute 32-slice 0..15
        int sp = (s + 8) & 15;
        int lk = kk * 32 + lg * 8;
        bf16x8 am[4], b0[4], b1[4];
#pragma unroll
        for (int m = 0; m < 4; ++m)
          am[m] = *(const bf16x8*)&As[h][(m * 16 + l15) * 136 + lk];
#pragma unroll
        for (int n = 0; n < 4; ++n) {
          const unsigned short* wr = wfk + (size_t)(wcol + n * 16 + l15) * 512;
          b0[n] = *(const bf16x8*)(wr + s * 32 + lg * 8);
          b1[n] = *(const bf16x8*)(wr + sp * 32 + lg * 8);
        }
#pragma unroll
        for (int m = 0; m < 4; ++m)
#pragma unroll
          for (int n = 0; n < 4; ++n) {
            acc[m][n] = __builtin_amdgcn_mfma_f32_16x16x32_bf16(am[m], b0[n], acc[m][n], 0, 0, 0);
            acc[m][n] = __builtin_amdgcn_mfma_f32_16x16x32_bf16(am[m], b1[n], acc[m][n], 0, 0, 0);
          }
      }
    }
  }
  // epilogue: relu(acc+bf)*alpha, reduce rows -> pooled
  int b = rowbase >> 12;
  float al[4][4];
#pragma unroll
  for (int m = 0; m < 4; ++m)
#pragma unroll
    for (int r = 0; r < 4; ++r)
      al[m][r] = alpha[rowbase + m * 16 + lg * 4 + r];
#pragma unroll
  for (int n = 0; n < 4; ++n) {
    int col = wcol + n * 16 + l15;
    float bv = bf[col];
    float po = 0.f;
#pragma unroll
    for (int m = 0; m < 4; ++m)
#pragma unroll
      for (int r = 0; r < 4; ++r)
        po += al[m][r] * fmaxf(acc[m][n][r] + bv, 0.f);
    po += __shfl_xor(po, 16, 64);
    po += __shfl_xor(po, 32, 64);
    if (lg == 0) atomicAdd(&pooled[(size_t)b * DF + col], po);
  }
}

// ---------------- out = pooled @ Wl + bl ----------------
__global__ __launch_bounds__(256) void final_kernel(
    const float* __restrict__ pooled, const float* __restrict__ Wl,
    const float* __restrict__ bl, float* __restrict__ out) {
  __shared__ float ps[DF];
  int b = blockIdx.x, j = threadIdx.x;
  for (int e = threadIdx.x; e < DF; e += 256) ps[e] = pooled[(size_t)b * DF + e];
  __syncthreads();
  float a0 = 0.f, a1 = 0.f, a2 = 0.f, a3 = 0.f;
  for (int o = 0; o < DF; o += 4) {
    a0 += ps[o + 0] * Wl[(size_t)(o + 0) * DOUT + j];
    a1 += ps[o + 1] * Wl[(size_t)(o + 1) * DOUT + j];
    a2 += ps[o + 2] * Wl[(size_t)(o + 2) * DOUT + j];
    a3 += ps[o + 3] * Wl[(size_t)(o + 3) * DOUT + j];
  }
  out[(size_t)b * DOUT + j] = (a0 + a1) + (a2 + a3) + bl[j];
}

// ---------------- launch ----------------
extern "C" void kernel_launch(void* const* d_in, const int* in_sizes, int n_in,
                              void* d_out, int out_size, void* d_ws, size_t ws_size,
                              hipStream_t stream) {
  (void)in_sizes; (void)n_in; (void)out_size; (void)ws_size;
  const float* x   = (const float*)d_in[0];
  const float* Wt0 = (const float*)d_in[1];
  const float* bt0 = (const float*)d_in[2];
  const float* Wp0 = (const float*)d_in[3];
  const float* bp0 = (const float*)d_in[4];
  const float* g0  = (const float*)d_in[5];
  const float* be0 = (const float*)d_in[6];
  const float* Wt1 = (const float*)d_in[7];
  const float* bt1 = (const float*)d_in[8];
  const float* Wp1 = (const float*)d_in[9];
  const float* bp1 = (const float*)d_in[10];
  const float* g1  = (const float*)d_in[11];
  const float* be1 = (const float*)d_in[12];
  const float* Wg  = (const float*)d_in[13];
  const float* bg  = (const float*)d_in[14];
  const float* Wf  = (const float*)d_in[15];
  const float* bf  = (const float*)d_in[16];
  const float* Wl  = (const float*)d_in[17];
  const float* bl  = (const float*)d_in[18];
  float* out = (float*)d_out;
  char* ws = (char*)d_ws;

  unsigned* VMM0 = (unsigned*)(ws + OFF_H0);
  int*   IDX0   = (int*)  (ws + OFF_IDX0);
  int*   IDX1   = (int*)  (ws + OFF_IDX1);
  float* D2     = (float*)(ws + OFF_D2);
  float* GATE   = (float*)(ws + OFF_GATE);
  float* ALPHA  = (float*)(ws + OFF_ALPHA);
  float* SS0    = (float*)(ws + OFF_SS0);
  float* SS1    = (float*)(ws + OFF_SS1);
  float* STATS0 = (float*)(ws + OFF_STATS0);
  float* STATS1 = (float*)(ws + OFF_STATS1);
  float* POOLED = (float*)(ws + OFF_POOLED);
  float* P1     = (float*)(ws + OFF_P1);
  float* Q1     = (float*)(ws + OFF_Q1);
  unsigned* VMM1 = (unsigned*)(ws + OFF_H1);
  unsigned short* AB1 = (unsigned short*)(ws + OFF_H1);   // in place over VMM1
  float* P0     = (float*)(ws + OFF_P0);
  float* Q0     = (float*)(ws + OFF_Q0);
  unsigned short* AB = (unsigned short*)(ws + OFF_AB);
  unsigned* PDU = (unsigned*)(ws + OFF_PDU);
  unsigned short* U0 = (unsigned short*)(ws + OFF_U0);
  unsigned short* V0 = (unsigned short*)(ws + OFF_V0);
  unsigned short* WQK = (unsigned short*)(ws + OFF_WQK);
  unsigned short* WFK = (unsigned short*)(ws + OFF_WFK);

  hipMemsetAsync(ws + ZERO_OFF, 0, ZERO_BYTES, stream);

  // weight preps (tiny)
  wprep1_kernel<<<512 * 64 / 256, 256, 0, stream>>>(Wt1, Wp1, WQK);
  wprepf_kernel<<<512 * 256 / 256, 256, 0, stream>>>(Wf, WFK);

  // ----- layer 0 -----
  d2x_kernel<<<BN / 256, 256, 0, stream>>>(x, D2);
  usplit0_kernel<<<BN / 256, 256, 0, stream>>>(x, U0, V0);
  knn_mfsel_kernel<32, 40, 8><<<(BN / 64) * 8, 256, 0, stream>>>(V0, U0, D2, PDU);
  knn_mergek_kernel<8><<<BN / 256, 256, 0, stream>>>(PDU, IDX0);
  pq0_kernel<<<BN * 64 / 256, 256, 0, stream>>>(x, Wt0, bt0, Wp0, bp0, P0, Q0);
  bn_gather_kernel<64, 32><<<BN / 32, 256, 0, stream>>>(P0, Q0, IDX0, STATS0, VMM0);
  bn_final_kernel<64><<<1, 64, 0, stream>>>(STATS0, g0, be0, SS0);
  apply0_kernel<<<BN / 4, 256, 0, stream>>>(VMM0, SS0, AB, D2);

  // ----- layer 1 -----
  knn_mfsel_kernel<128, 136, 8><<<(BN / 64) * 8, 256, 0, stream>>>(AB, AB, D2, PDU);
  knn_mergek_kernel<8><<<BN / 256, 256, 0, stream>>>(PDU, IDX1);
  gemm_pq1_kernel<<<(BN / 64) * 2, 256, 0, stream>>>(AB, WQK, bt1, bp1, P1, Q1);
  bn_gather_kernel<256, 16><<<BN / 16, 256, 0, stream>>>(P1, Q1, IDX1, STATS1, VMM1);
  bn_final_kernel<256><<<1, 256, 0, stream>>>(STATS1, g1, be1, SS1);
  apply1_kernel<<<BN / 4, 256, 0, stream>>>(VMM1, SS1, Wg, bg, AB1, GATE);

  // ----- pooling + final -----
  softmax_kernel<<<NBATCH, 256, 0, stream>>>(GATE, ALPHA);
  gemm_fp_kernel<<<(BN / 64) * 2, 256, 0, stream>>>(AB1, WFK, bf, ALPHA, POOLED);
  final_kernel<<<NBATCH, 256, 0, stream>>>(POOLED, Wl, bl, out);
}

// Round 9
// 417.237 us; speedup vs baseline: 1.2890x; 1.2890x over previous
//
#include <hip/hip_runtime.h>
#include <hip/hip_bf16.h>
#include <math.h>

// ---------------- problem constants ----------------
static constexpr int NBATCH = 4;
static constexpr int NPTS   = 4096;
static constexpr int BN     = NBATCH * NPTS;   // 16384
static constexpr int KNN    = 20;
static constexpr float BN_EPS = 1e-5f;
static constexpr float SLOPE  = 0.2f;
static constexpr int DF = 512, DOUT = 256;

#define FINF __builtin_huge_valf()

typedef short bf16x8 __attribute__((ext_vector_type(8)));
typedef float f32x4  __attribute__((ext_vector_type(4)));

// ---------------- workspace layout (bytes) ----------------
static constexpr size_t OFF_H0     = 0;                    // 4 MB: VMM0
static constexpr size_t OFF_IDX0   = 4194304;              // 1.25 MB
static constexpr size_t OFF_IDX1   = 5505024;              // 1.25 MB
static constexpr size_t OFF_D2     = 6815744;              // 64 KB
static constexpr size_t OFF_GATE   = 6881280;              // 64 KB
static constexpr size_t OFF_ALPHA  = 6946816;              // 64 KB
static constexpr size_t OFF_SS0    = 7012352;
static constexpr size_t OFF_SS1    = 7012864;
static constexpr size_t OFF_STATS0 = 7014912;
static constexpr size_t OFF_STATS1 = 7015424;
static constexpr size_t OFF_POOLED = 7017472;              // -> 7,025,664
static constexpr size_t ZERO_OFF   = OFF_STATS0;
static constexpr size_t ZERO_BYTES = 7025664 - 7014912;
static constexpr size_t OFF_P1     = 7025664;              // 8 MB bf16 (gemm_pq1 out)
static constexpr size_t OFF_PDU    = OFF_P1;               // S=4: 5.24 MB (dead before P1)
static constexpr size_t OFF_WQK    = 23802880;             // 512*128*2
static constexpr size_t OFF_WFK    = 23933952;             // 512*512*2 -> 24,458,240
static constexpr size_t OFF_Q1     = 27997184;             // 8 MB bf16
static constexpr size_t OFF_U0     = OFF_Q1;               // 1 MB (dead before P0)
static constexpr size_t OFF_V0     = OFF_Q1 + 1048576;     // 1 MB
static constexpr size_t OFF_P0     = OFF_Q1;               // 2 MB bf16
static constexpr size_t OFF_Q0     = OFF_Q1 + 2097152;     // 2 MB bf16
static constexpr size_t OFF_H1     = 44774400;             // 16 MB: VMM1 then AB1 (in place)
static constexpr size_t OFF_AB     = 61551616;             // 4 MB -> 65,745,920

// ---------------- helpers ----------------
__device__ inline unsigned short f2bf_rne(float x) {
  unsigned int u = __float_as_uint(x);
  unsigned int lsb = (u >> 16) & 1u;
  u += 0x7fffu + lsb;
  return (unsigned short)(u >> 16);
}
__device__ inline float bf2f(unsigned short s) {
  return __uint_as_float((unsigned int)s << 16);
}
__device__ inline unsigned umn(unsigned a, unsigned b) { return a < b ? a : b; }
// clamp(v,lo,hi), lo<=hi == sorted-insert slot update; identity when v>=hi.
// asm v_med3_u32: PROVEN fastest form (R7 vs R8 A/B: min+max pair doubles VALU).
__device__ inline unsigned umed3(unsigned v, unsigned lo, unsigned hi) {
  unsigned d;
  asm("v_med3_u32 %0, %1, %2, %3" : "=v"(d) : "v"(v), "v"(lo), "v"(hi));
  return d;
}

// ---------------- d2 = sum(x*x), D=3 ----------------
__global__ __launch_bounds__(256) void d2x_kernel(const float* __restrict__ x,
                                                  float* __restrict__ d2) {
  int n = blockIdx.x * 256 + threadIdx.x;
  const float* r = x + (size_t)n * 3;
  d2[n] = r[0] * r[0] + r[1] * r[1] + r[2] * r[2];
}

// ---------------- layer-0 packing: U=[A,B,A,B,0..] (queries), V=[A,A,B,B,0..] ----
__global__ __launch_bounds__(256) void usplit0_kernel(
    const float* __restrict__ x, unsigned short* __restrict__ U0,
    unsigned short* __restrict__ V0) {
  int n = blockIdx.x * 256 + threadIdx.x;
  float v0 = x[(size_t)n * 3], v1 = x[(size_t)n * 3 + 1], v2 = x[(size_t)n * 3 + 2];
  unsigned short A0 = f2bf_rne(v0), A1 = f2bf_rne(v1), A2 = f2bf_rne(v2);
  unsigned short B0 = f2bf_rne(v0 - bf2f(A0));
  unsigned short B1 = f2bf_rne(v1 - bf2f(A1));
  unsigned short B2 = f2bf_rne(v2 - bf2f(A2));
  ushort4 z = make_ushort4(0, 0, 0, 0);
  unsigned short* up = U0 + ((size_t)n << 5);
  ((ushort4*)up)[0] = make_ushort4(A0, A1, A2, B0);
  ((ushort4*)up)[1] = make_ushort4(B1, B2, A0, A1);
  ((ushort4*)up)[2] = make_ushort4(A2, B0, B1, B2);
  ((ushort4*)up)[3] = z; ((ushort4*)up)[4] = z; ((ushort4*)up)[5] = z;
  ((ushort4*)up)[6] = z; ((ushort4*)up)[7] = z;
  unsigned short* vp = V0 + ((size_t)n << 5);
  ((ushort4*)vp)[0] = make_ushort4(A0, A1, A2, A0);
  ((ushort4*)vp)[1] = make_ushort4(A1, A2, B0, B1);
  ((ushort4*)vp)[2] = make_ushort4(B2, B0, B1, B2);
  ((ushort4*)vp)[3] = z; ((ushort4*)vp)[4] = z; ((ushort4*)vp)[5] = z;
  ((ushort4*)vp)[6] = z; ((ushort4*)vp)[7] = z;
}

// ---------------- unified MFMA KNN with in-register med3 selection ----------------
template<int KW, int CST, int S>
__global__ __launch_bounds__(256, 4) void knn_mfsel_kernel(
    const unsigned short* __restrict__ cab,
    const unsigned short* __restrict__ qab,
    const float* __restrict__ d2,
    unsigned* __restrict__ pdu) {
  constexpr int CS = NPTS / S, NCH = CS / 32;
  __shared__ __align__(16) unsigned short cbuf[2][32 * CST];
  __shared__ __align__(16) float cd2b[2][32];

  int bid = blockIdx.x;
  int s   = bid & (S - 1);
  int qb  = bid / S;
  int b   = qb >> 6;
  int qloc = (qb & 63) * 64;
  int wv = threadIdx.x >> 6, lane = threadIdx.x & 63;
  int l15 = lane & 15, lg = lane >> 4;
  int qg = b * NPTS + qloc + wv * 16 + l15;

  bf16x8 af[KW / 32];
#pragma unroll
  for (int kk = 0; kk < KW / 32; ++kk)
    af[kk] = *(const bf16x8*)(qab + (size_t)qg * KW + kk * 32 + lg * 8);
  float d2q = d2[qg];

  unsigned bd[KNN];
#pragma unroll
  for (int k = 0; k < KNN; ++k) bd[k] = 0xFFFFFFFFu;

  int scand = threadIdx.x >> 3, sseg = threadIdx.x & 7;
  const unsigned short* sbase = cab + ((size_t)(b * NPTS + s * CS)) * KW;
  const float* d2base = d2 + b * NPTS + s * CS;

  bf16x8 r0, r1;
  ushort4 r2;
  float rd2 = 0.f;

  if constexpr (KW == 128) {
    const unsigned short* src = sbase + (size_t)scand * KW + sseg * 16;
    r0 = *(const bf16x8*)src;
    r1 = *(const bf16x8*)(src + 8);
    *(bf16x8*)&cbuf[0][scand * CST + sseg * 16]     = r0;
    *(bf16x8*)&cbuf[0][scand * CST + sseg * 16 + 8] = r1;
  } else {
    r2 = *(const ushort4*)(sbase + (size_t)scand * KW + sseg * 4);
    *(ushort4*)&cbuf[0][scand * CST + sseg * 4] = r2;
  }
  if (threadIdx.x < 32) cd2b[0][threadIdx.x] = d2base[threadIdx.x];
  __syncthreads();

#pragma unroll 1
  for (int ch = 0; ch < NCH; ++ch) {
    int cur = ch & 1;
    if (ch < NCH - 1) {
      if constexpr (KW == 128) {
        const unsigned short* src = sbase + (size_t)(32 * (ch + 1) + scand) * KW + sseg * 16;
        r0 = *(const bf16x8*)src;
        r1 = *(const bf16x8*)(src + 8);
      } else {
        r2 = *(const ushort4*)(sbase + (size_t)(32 * (ch + 1) + scand) * KW + sseg * 4);
      }
      if (threadIdx.x < 32) rd2 = d2base[32 * (ch + 1) + threadIdx.x];
    }

    f32x4 acc0 = (f32x4){0.f, 0.f, 0.f, 0.f};
    f32x4 acc1 = (f32x4){0.f, 0.f, 0.f, 0.f};
    if constexpr (KW == 128) {
#pragma unroll
      for (int j = 0; j < 4; ++j) {
        int koff = j * 32 + lg * 8;
        bf16x8 a0 = *(const bf16x8*)&cbuf[cur][l15 * CST + koff];
        bf16x8 a1 = *(const bf16x8*)&cbuf[cur][(16 + l15) * CST + koff];
        acc0 = __builtin_amdgcn_mfma_f32_16x16x32_bf16(a0, af[j], acc0, 0, 0, 0);
        acc0 = __builtin_amdgcn_mfma_f32_16x16x32_bf16(a0, af[(j + 2) & 3], acc0, 0, 0, 0);
        acc1 = __builtin_amdgcn_mfma_f32_16x16x32_bf16(a1, af[j], acc1, 0, 0, 0);
        acc1 = __builtin_amdgcn_mfma_f32_16x16x32_bf16(a1, af[(j + 2) & 3], acc1, 0, 0, 0);
      }
    } else {
      bf16x8 a0 = *(const bf16x8*)&cbuf[cur][l15 * CST + lg * 8];
      bf16x8 a1 = *(const bf16x8*)&cbuf[cur][(16 + l15) * CST + lg * 8];
      acc0 = __builtin_amdgcn_mfma_f32_16x16x32_bf16(a0, af[0], acc0, 0, 0, 0);
      acc1 = __builtin_amdgcn_mfma_f32_16x16x32_bf16(a1, af[0], acc1, 0, 0, 0);
    }

    int cb = s * CS + ch * 32;
#pragma unroll
    for (int t = 0; t < 2; ++t) {
      f32x4 cd4 = *(const f32x4*)&cd2b[cur][t * 16 + lg * 4];
      f32x4 ac = t ? acc1 : acc0;
#pragma unroll
      for (int r = 0; r < 4; ++r) {
        float dist = fmaxf(fmaf(-2.f, ac[r], d2q + cd4[r]), 0.f);
        unsigned key = (__float_as_uint(dist) & 0xFFFFF000u)
                     | (unsigned)(cb + t * 16 + lg * 4 + r);
        // unconditional sorted-insert: identity when key >= bd[19]
#pragma unroll
        for (int t_ = KNN - 1; t_ >= 1; --t_) bd[t_] = umed3(key, bd[t_ - 1], bd[t_]);
        bd[0] = umn(bd[0], key);
      }
    }

    if (ch < NCH - 1) {
      if constexpr (KW == 128) {
        *(bf16x8*)&cbuf[cur ^ 1][scand * CST + sseg * 16]     = r0;
        *(bf16x8*)&cbuf[cur ^ 1][scand * CST + sseg * 16 + 8] = r1;
      } else {
        *(ushort4*)&cbuf[cur ^ 1][scand * CST + sseg * 4] = r2;
      }
      if (threadIdx.x < 32) cd2b[cur ^ 1][threadIdx.x] = rd2;
    }
    __syncthreads();
  }

  // merge 4 per-lane sorted lists via shuffles into lg==0 lanes (exact union)
#pragma unroll 1
  for (int li = 1; li < 4; ++li) {
#pragma unroll 1
    for (int k = 0; k < KNN; ++k) {
      unsigned v = __shfl(bd[k], l15 + li * 16, 64);
      if (lg == 0 && v < bd[KNN - 1]) {
#pragma unroll
        for (int t_ = KNN - 1; t_ >= 1; --t_) bd[t_] = umed3(v, bd[t_ - 1], bd[t_]);
        bd[0] = umn(bd[0], v);
      }
    }
  }
  if (lg == 0) {
    unsigned* dst = pdu + ((size_t)(b * NPTS + qloc + wv * 16 + l15) * S + s) * KNN;
#pragma unroll
    for (int k = 0; k < KNN; ++k) dst[k] = bd[k];
  }
}

// ---------------- merge S sorted packed-key lists -> idx ----------------
template<int S>
__global__ __launch_bounds__(256) void knn_mergek_kernel(
    const unsigned* __restrict__ pdu, int* __restrict__ idx) {
  int n = blockIdx.x * 256 + threadIdx.x;
  const unsigned* l0 = pdu + (size_t)n * S * KNN;
  unsigned bd[KNN];
#pragma unroll
  for (int k = 0; k < KNN; ++k) bd[k] = l0[k];
#pragma unroll 1
  for (int s = 1; s < S; ++s) {
#pragma unroll 1
    for (int k = 0; k < KNN; ++k) {
      unsigned v = l0[s * KNN + k];
      if (!(v < bd[KNN - 1])) break;
#pragma unroll
      for (int t_ = KNN - 1; t_ >= 1; --t_) bd[t_] = umed3(v, bd[t_ - 1], bd[t_]);
      bd[0] = umn(bd[0], v);
    }
  }
#pragma unroll
  for (int k = 0; k < KNN; ++k) idx[(size_t)n * KNN + k] = (int)(bd[k] & 0xFFFu);
}

// ---------------- EdgeConv0: P,Q projections (D=3), bf16 outputs ----------------
__global__ __launch_bounds__(256) void pq0_kernel(
    const float* __restrict__ x,
    const float* __restrict__ Wt, const float* __restrict__ bt,
    const float* __restrict__ Wp, const float* __restrict__ bp,
    unsigned short* __restrict__ P0, unsigned short* __restrict__ Q0) {
  int t = blockIdx.x * 256 + threadIdx.x;
  int c = t & 63, n = t >> 6;
  const float* xr = x + (size_t)n * 3;
  float x0 = xr[0], x1 = xr[1], x2 = xr[2];
  float wt0 = Wt[0 * 64 + c], wt1 = Wt[1 * 64 + c], wt2 = Wt[2 * 64 + c];
  float wp0 = Wp[0 * 64 + c], wp1 = Wp[1 * 64 + c], wp2 = Wp[2 * 64 + c];
  P0[t] = f2bf_rne(x0 * wt0 + x1 * wt1 + x2 * wt2 + bt[c] + bp[c]);
  Q0[t] = f2bf_rne(x0 * (wp0 - wt0) + x1 * (wp1 - wt1) + x2 * (wp2 - wt2));
}

// ---------------- fused BN gather (bf16 P,Q): stats + per-(n,c) bf16 vmax/vmin ----
template<int C, int PB>
__global__ __launch_bounds__(256) void bn_gather_kernel(
    const unsigned short* __restrict__ P, const unsigned short* __restrict__ Q,
    const int* __restrict__ idx, float* __restrict__ stats,
    unsigned* __restrict__ vmm) {
  constexpr int G = 256 / C;
  int c = threadIdx.x % C;
  int g = threadIdx.x / C;
  int p0 = blockIdx.x * PB;
  float sum = 0.f, sq = 0.f;
  for (int p = g; p < PB; p += G) {
    int n = p0 + p;
    int b = n >> 12;
    float pc = bf2f(P[(size_t)n * C + c]);
    const int* id = idx + (size_t)n * KNN;
    float vmax = -FINF, vmin = FINF;
#pragma unroll
    for (int k = 0; k < KNN; ++k) {
      int j = id[k];
      float v = pc + bf2f(Q[((size_t)(b << 12) + j) * C + c]);
      sum += v; sq += v * v;
      vmax = fmaxf(vmax, v); vmin = fminf(vmin, v);
    }
    vmm[(size_t)n * C + c] = ((unsigned)f2bf_rne(vmax) << 16) | f2bf_rne(vmin);
  }
  if constexpr (G > 1) {
    __shared__ float ls[2][256];
    ls[0][threadIdx.x] = sum; ls[1][threadIdx.x] = sq;
    __syncthreads();
    if (g == 0) {
#pragma unroll
      for (int gg = 1; gg < G; ++gg) { sum += ls[0][gg * C + c]; sq += ls[1][gg * C + c]; }
      atomicAdd(&stats[c], sum); atomicAdd(&stats[C + c], sq);
    }
  } else {
    atomicAdd(&stats[c], sum); atomicAdd(&stats[C + c], sq);
  }
}

template<int C>
__global__ void bn_final_kernel(const float* __restrict__ stats,
                                const float* __restrict__ gamma,
                                const float* __restrict__ beta,
                                float* __restrict__ ss) {
  int c = threadIdx.x;
  if (c < C) {
    const float cnt = (float)((size_t)BN * KNN);
    float mu  = stats[c] / cnt;
    float var = stats[C + c] / cnt - mu * mu;
    float sc  = gamma[c] * rsqrtf(var + BN_EPS);
    ss[c] = sc;
    ss[C + c] = beta[c] - mu * sc;
  }
}

// ---------------- apply0: affine+lrelu from vmm0 -> AB split + D2 ----------------
__global__ __launch_bounds__(256) void apply0_kernel(
    const unsigned* __restrict__ vmm, const float* __restrict__ ss,
    unsigned short* __restrict__ ab, float* __restrict__ d2) {
  int wv = threadIdx.x >> 6, lane = threadIdx.x & 63;
  int n = blockIdx.x * 4 + wv;
  unsigned pk = vmm[(size_t)n * 64 + lane];
  float sc = ss[lane], sh = ss[64 + lane];
  float vmax = bf2f((unsigned short)(pk >> 16));
  float vmin = bf2f((unsigned short)(pk & 0xFFFFu));
  float m = (sc >= 0.f) ? vmax : vmin;
  float y = fmaf(m, sc, sh);
  y = (y >= 0.f) ? y : SLOPE * y;
  unsigned short a = f2bf_rne(y);
  unsigned short b = f2bf_rne(y - bf2f(a));
  ab[(size_t)n * 128 + lane] = a;
  ab[(size_t)n * 128 + 64 + lane] = b;
  float s = y * y;
#pragma unroll
  for (int off = 32; off >= 1; off >>= 1) s += __shfl_down(s, off);
  if (lane == 0) d2[n] = s;
}

// ---------------- weight prep: Wqk[512 outcol][128 k] = split([Wt | Wp-Wt]) ------
__global__ __launch_bounds__(256) void wprep1_kernel(
    const float* __restrict__ Wt, const float* __restrict__ Wp,
    unsigned short* __restrict__ wqk) {
  int t = blockIdx.x * 256 + threadIdx.x;   // over 512*64
  int o = t >> 6, k = t & 63;
  float w;
  if (o < 256) w = Wt[(size_t)k * 256 + o];
  else { int oo = o - 256; w = Wp[(size_t)k * 256 + oo] - Wt[(size_t)k * 256 + oo]; }
  unsigned short a = f2bf_rne(w);
  wqk[(size_t)o * 128 + k]      = a;
  wqk[(size_t)o * 128 + 64 + k] = f2bf_rne(w - bf2f(a));
}

// ---------------- weight prep: Wfk[512 outcol][512 k] = split(Wf) ----------------
__global__ __launch_bounds__(256) void wprepf_kernel(
    const float* __restrict__ Wf, unsigned short* __restrict__ wfk) {
  int t = blockIdx.x * 256 + threadIdx.x;   // over 512*256
  int o = t >> 8, k = t & 255;
  float w = Wf[(size_t)k * 512 + o];
  unsigned short a = f2bf_rne(w);
  wfk[(size_t)o * 512 + k]       = a;
  wfk[(size_t)o * 512 + 256 + k] = f2bf_rne(w - bf2f(a));
}

// ---------------- gemm_pq1: [BN,128sp]@[128sp,512] -> bf16 P1|Q1, bias fused ----
__global__ __launch_bounds__(256, 2) void gemm_pq1_kernel(
    const unsigned short* __restrict__ ab, const unsigned short* __restrict__ wqk,
    const float* __restrict__ bt, const float* __restrict__ bp,
    unsigned short* __restrict__ P1, unsigned short* __restrict__ Q1) {
  __shared__ __align__(16) unsigned short As[64 * 136];
  int cb = blockIdx.x & 1;
  int rb = blockIdx.x >> 1;
  int wv = threadIdx.x >> 6, lane = threadIdx.x & 63;
  int l15 = lane & 15, lg = lane >> 4;
  {
    int row = threadIdx.x >> 2, seg = threadIdx.x & 3;
    const unsigned short* src = ab + ((size_t)(rb * 64 + row)) * 128 + seg * 32;
    *(bf16x8*)&As[row * 136 + seg * 32]      = *(const bf16x8*)(src);
    *(bf16x8*)&As[row * 136 + seg * 32 + 8]  = *(const bf16x8*)(src + 8);
    *(bf16x8*)&As[row * 136 + seg * 32 + 16] = *(const bf16x8*)(src + 16);
    *(bf16x8*)&As[row * 136 + seg * 32 + 24] = *(const bf16x8*)(src + 24);
  }
  __syncthreads();
  int wcol = cb * 256 + wv * 64;
  f32x4 acc[4][4];
#pragma unroll
  for (int m = 0; m < 4; ++m)
#pragma unroll
    for (int n = 0; n < 4; ++n) acc[m][n] = (f32x4){0.f, 0.f, 0.f, 0.f};
#pragma unroll
  for (int kk = 0; kk < 4; ++kk) {
    int k0 = kk * 32 + lg * 8;
    int k1 = ((kk + 2) & 3) * 32 + lg * 8;
    bf16x8 am[4], b0[4], b1[4];
#pragma unroll
    for (int m = 0; m < 4; ++m)
      am[m] = *(const bf16x8*)&As[(m * 16 + l15) * 136 + k0];
#pragma unroll
    for (int n = 0; n < 4; ++n) {
      const unsigned short* wr = wqk + (size_t)(wcol + n * 16 + l15) * 128;
      b0[n] = *(const bf16x8*)(wr + k0);
      b1[n] = *(const bf16x8*)(wr + k1);
    }
#pragma unroll
    for (int m = 0; m < 4; ++m)
#pragma unroll
      for (int n = 0; n < 4; ++n) {
        acc[m][n] = __builtin_amdgcn_mfma_f32_16x16x32_bf16(am[m], b0[n], acc[m][n], 0, 0, 0);
        acc[m][n] = __builtin_amdgcn_mfma_f32_16x16x32_bf16(am[m], b1[n], acc[m][n], 0, 0, 0);
      }
  }
#pragma unroll
  for (int n = 0; n < 4; ++n) {
    int col = wcol + n * 16 + l15;
    bool isP = col < 256;
    float bias = isP ? (bt[col] + bp[col]) : 0.f;
    unsigned short* dst = isP ? (P1 + col) : (Q1 + (col - 256));
#pragma unroll
    for (int m = 0; m < 4; ++m)
#pragma unroll
      for (int r = 0; r < 4; ++r) {
        int row = rb * 64 + m * 16 + lg * 4 + r;
        dst[(size_t)row * 256] = f2bf_rne(acc[m][n][r] + bias);
      }
  }
}

// ---------------- apply1: vmm1 -> AB1 (in place) + gate ----------------
__global__ __launch_bounds__(256) void apply1_kernel(
    const unsigned* __restrict__ vmm, const float* __restrict__ ss,
    const float* __restrict__ Wg, const float* __restrict__ bg,
    unsigned short* __restrict__ ab1, float* __restrict__ gate) {
  int wv = threadIdx.x >> 6, lane = threadIdx.x & 63;
  int n = blockIdx.x * 4 + wv;
  unsigned pk[4];
#pragma unroll
  for (int i = 0; i < 4; ++i) pk[i] = vmm[(size_t)n * 256 + lane + 64 * i];  // reads first
  float gsum = 0.f;
  unsigned short Aa[4], Bb[4];
#pragma unroll
  for (int i = 0; i < 4; ++i) {
    int c = lane + 64 * i;
    float sc = ss[c], sh = ss[256 + c];
    float vmax = bf2f((unsigned short)(pk[i] >> 16));
    float vmin = bf2f((unsigned short)(pk[i] & 0xFFFFu));
    float m = (sc >= 0.f) ? vmax : vmin;
    float y = fmaf(m, sc, sh);
    y = (y >= 0.f) ? y : SLOPE * y;
    Aa[i] = f2bf_rne(y);
    Bb[i] = f2bf_rne(y - bf2f(Aa[i]));
    gsum += y * Wg[c];
  }
#pragma unroll
  for (int i = 0; i < 4; ++i) {
    ab1[(size_t)n * 512 + lane + 64 * i]       = Aa[i];
    ab1[(size_t)n * 512 + 256 + lane + 64 * i] = Bb[i];
  }
#pragma unroll
  for (int off = 32; off >= 1; off >>= 1) gsum += __shfl_down(gsum, off);
  if (lane == 0) gate[n] = fmaxf(gsum + bg[0], 0.f);
}

// ---------------- softmax over N per batch ----------------
__global__ void softmax_kernel(const float* __restrict__ gate,
                               float* __restrict__ alpha) {
  __shared__ float red[256];
  int b = blockIdx.x;
  const float* g = gate + (size_t)b * NPTS;
  float* a = alpha + (size_t)b * NPTS;
  float m = -FINF;
  for (int i = threadIdx.x; i < NPTS; i += 256) m = fmaxf(m, g[i]);
  red[threadIdx.x] = m; __syncthreads();
  for (int st = 128; st >= 1; st >>= 1) {
    if (threadIdx.x < st) red[threadIdx.x] = fmaxf(red[threadIdx.x], red[threadIdx.x + st]);
    __syncthreads();
  }
  m = red[0]; __syncthreads();
  float s = 0.f;
  for (int i = threadIdx.x; i < NPTS; i += 256) s += expf(g[i] - m);
  red[threadIdx.x] = s; __syncthreads();
  for (int st = 128; st >= 1; st >>= 1) {
    if (threadIdx.x < st) red[threadIdx.x] += red[threadIdx.x + st];
    __syncthreads();
  }
  float inv = 1.f / red[0];
  for (int i = threadIdx.x; i < NPTS; i += 256) a[i] = expf(g[i] - m) * inv;
}

// ---------------- gemm_fp: feat GEMM (split, K=512) + relu + alpha-pool ----------
__global__ __launch_bounds__(256, 2) void gemm_fp_kernel(
    const unsigned short* __restrict__ ab1, const unsigned short* __restrict__ wfk,
    const float* __restrict__ bf, const float* __restrict__ alpha,
    float* __restrict__ pooled) {
  __shared__ __align__(16) unsigned short As[2][64 * 136];
  int cb = blockIdx.x & 1;
  int rb = blockIdx.x >> 1;
  int wv = threadIdx.x >> 6, lane = threadIdx.x & 63;
  int l15 = lane & 15, lg = lane >> 4;
  int wcol = cb * 256 + wv * 64;
  int rowbase = rb * 64;
  f32x4 acc[4][4];
#pragma unroll
  for (int m = 0; m < 4; ++m)
#pragma unroll
    for (int n = 0; n < 4; ++n) acc[m][n] = (f32x4){0.f, 0.f, 0.f, 0.f};

#pragma unroll 1
  for (int kc = 0; kc < 2; ++kc) {
    __syncthreads();
    {
      int row = threadIdx.x >> 2, seg = threadIdx.x & 3;
      const unsigned short* s0 = ab1 + ((size_t)(rowbase + row)) * 512 + kc * 128 + seg * 32;
      const unsigned short* s1 = s0 + 256;
#pragma unroll
      for (int u = 0; u < 4; ++u) {
        *(bf16x8*)&As[0][row * 136 + seg * 32 + u * 8] = *(const bf16x8*)(s0 + u * 8);
        *(bf16x8*)&As[1][row * 136 + seg * 32 + u * 8] = *(const bf16x8*)(s1 + u * 8);
      }
    }
    __syncthreads();
#pragma unroll
    for (int h = 0; h < 2; ++h) {
#pragma unroll
      for (int kk = 0; kk < 4; ++kk) {
        int s  = kc * 4 + h * 8 + kk;
        int sp = (s + 8) & 15;
        int lk = kk * 32 + lg * 8;
        bf16x8 am[4], b0[4], b1[4];
#pragma unroll
        for (int m = 0; m < 4; ++m)
          am[m] = *(const bf16x8*)&As[h][(m * 16 + l15) * 136 + lk];
#pragma unroll
        for (int n = 0; n < 4; ++n) {
          const unsigned short* wr = wfk + (size_t)(wcol + n * 16 + l15) * 512;
          b0[n] = *(const bf16x8*)(wr + s * 32 + lg * 8);
          b1[n] = *(const bf16x8*)(wr + sp * 32 + lg * 8);
        }
#pragma unroll
        for (int m = 0; m < 4; ++m)
#pragma unroll
          for (int n = 0; n < 4; ++n) {
            acc[m][n] = __builtin_amdgcn_mfma_f32_16x16x32_bf16(am[m], b0[n], acc[m][n], 0, 0, 0);
            acc[m][n] = __builtin_amdgcn_mfma_f32_16x16x32_bf16(am[m], b1[n], acc[m][n], 0, 0, 0);
          }
      }
    }
  }
  int b = rowbase >> 12;
  float al[4][4];
#pragma unroll
  for (int m = 0; m < 4; ++m)
#pragma unroll
    for (int r = 0; r < 4; ++r)
      al[m][r] = alpha[rowbase + m * 16 + lg * 4 + r];
#pragma unroll
  for (int n = 0; n < 4; ++n) {
    int col = wcol + n * 16 + l15;
    float bv = bf[col];
    float po = 0.f;
#pragma unroll
    for (int m = 0; m < 4; ++m)
#pragma unroll
      for (int r = 0; r < 4; ++r)
        po += al[m][r] * fmaxf(acc[m][n][r] + bv, 0.f);
    po += __shfl_xor(po, 16, 64);
    po += __shfl_xor(po, 32, 64);
    if (lg == 0) atomicAdd(&pooled[(size_t)b * DF + col], po);
  }
}

// ---------------- out = pooled @ Wl + bl ----------------
__global__ __launch_bounds__(256) void final_kernel(
    const float* __restrict__ pooled, const float* __restrict__ Wl,
    const float* __restrict__ bl, float* __restrict__ out) {
  __shared__ float ps[DF];
  int b = blockIdx.x, j = threadIdx.x;
  for (int e = threadIdx.x; e < DF; e += 256) ps[e] = pooled[(size_t)b * DF + e];
  __syncthreads();
  float a0 = 0.f, a1 = 0.f, a2 = 0.f, a3 = 0.f;
  for (int o = 0; o < DF; o += 4) {
    a0 += ps[o + 0] * Wl[(size_t)(o + 0) * DOUT + j];
    a1 += ps[o + 1] * Wl[(size_t)(o + 1) * DOUT + j];
    a2 += ps[o + 2] * Wl[(size_t)(o + 2) * DOUT + j];
    a3 += ps[o + 3] * Wl[(size_t)(o + 3) * DOUT + j];
  }
  out[(size_t)b * DOUT + j] = (a0 + a1) + (a2 + a3) + bl[j];
}

// ---------------- launch ----------------
extern "C" void kernel_launch(void* const* d_in, const int* in_sizes, int n_in,
                              void* d_out, int out_size, void* d_ws, size_t ws_size,
                              hipStream_t stream) {
  (void)in_sizes; (void)n_in; (void)out_size; (void)ws_size;
  const float* x   = (const float*)d_in[0];
  const float* Wt0 = (const float*)d_in[1];
  const float* bt0 = (const float*)d_in[2];
  const float* Wp0 = (const float*)d_in[3];
  const float* bp0 = (const float*)d_in[4];
  const float* g0  = (const float*)d_in[5];
  const float* be0 = (const float*)d_in[6];
  const float* Wt1 = (const float*)d_in[7];
  const float* bt1 = (const float*)d_in[8];
  const float* Wp1 = (const float*)d_in[9];
  const float* bp1 = (const float*)d_in[10];
  const float* g1  = (const float*)d_in[11];
  const float* be1 = (const float*)d_in[12];
  const float* Wg  = (const float*)d_in[13];
  const float* bg  = (const float*)d_in[14];
  const float* Wf  = (const float*)d_in[15];
  const float* bf  = (const float*)d_in[16];
  const float* Wl  = (const float*)d_in[17];
  const float* bl  = (const float*)d_in[18];
  float* out = (float*)d_out;
  char* ws = (char*)d_ws;

  unsigned* VMM0 = (unsigned*)(ws + OFF_H0);
  int*   IDX0   = (int*)  (ws + OFF_IDX0);
  int*   IDX1   = (int*)  (ws + OFF_IDX1);
  float* D2     = (float*)(ws + OFF_D2);
  float* GATE   = (float*)(ws + OFF_GATE);
  float* ALPHA  = (float*)(ws + OFF_ALPHA);
  float* SS0    = (float*)(ws + OFF_SS0);
  float* SS1    = (float*)(ws + OFF_SS1);
  float* STATS0 = (float*)(ws + OFF_STATS0);
  float* STATS1 = (float*)(ws + OFF_STATS1);
  float* POOLED = (float*)(ws + OFF_POOLED);
  unsigned short* P1 = (unsigned short*)(ws + OFF_P1);
  unsigned short* Q1 = (unsigned short*)(ws + OFF_Q1);
  unsigned* VMM1 = (unsigned*)(ws + OFF_H1);
  unsigned short* AB1 = (unsigned short*)(ws + OFF_H1);   // in place over VMM1
  unsigned short* P0 = (unsigned short*)(ws + OFF_P0);
  unsigned short* Q0 = (unsigned short*)(ws + OFF_Q0);
  unsigned short* AB = (unsigned short*)(ws + OFF_AB);
  unsigned* PDU = (unsigned*)(ws + OFF_PDU);
  unsigned short* U0 = (unsigned short*)(ws + OFF_U0);
  unsigned short* V0 = (unsigned short*)(ws + OFF_V0);
  unsigned short* WQK = (unsigned short*)(ws + OFF_WQK);
  unsigned short* WFK = (unsigned short*)(ws + OFF_WFK);

  hipMemsetAsync(ws + ZERO_OFF, 0, ZERO_BYTES, stream);

  // weight preps (tiny)
  wprep1_kernel<<<512 * 64 / 256, 256, 0, stream>>>(Wt1, Wp1, WQK);
  wprepf_kernel<<<512 * 256 / 256, 256, 0, stream>>>(Wf, WFK);

  // ----- layer 0 -----
  d2x_kernel<<<BN / 256, 256, 0, stream>>>(x, D2);
  usplit0_kernel<<<BN / 256, 256, 0, stream>>>(x, U0, V0);
  knn_mfsel_kernel<32, 40, 4><<<(BN / 64) * 4, 256, 0, stream>>>(V0, U0, D2, PDU);
  knn_mergek_kernel<4><<<BN / 256, 256, 0, stream>>>(PDU, IDX0);
  pq0_kernel<<<BN * 64 / 256, 256, 0, stream>>>(x, Wt0, bt0, Wp0, bp0, P0, Q0);
  bn_gather_kernel<64, 32><<<BN / 32, 256, 0, stream>>>(P0, Q0, IDX0, STATS0, VMM0);
  bn_final_kernel<64><<<1, 64, 0, stream>>>(STATS0, g0, be0, SS0);
  apply0_kernel<<<BN / 4, 256, 0, stream>>>(VMM0, SS0, AB, D2);

  // ----- layer 1 -----
  knn_mfsel_kernel<128, 136, 4><<<(BN / 64) * 4, 256, 0, stream>>>(AB, AB, D2, PDU);
  knn_mergek_kernel<4><<<BN / 256, 256, 0, stream>>>(PDU, IDX1);
  gemm_pq1_kernel<<<(BN / 64) * 2, 256, 0, stream>>>(AB, WQK, bt1, bp1, P1, Q1);
  bn_gather_kernel<256, 16><<<BN / 16, 256, 0, stream>>>(P1, Q1, IDX1, STATS1, VMM1);
  bn_final_kernel<256><<<1, 256, 0, stream>>>(STATS1, g1, be1, SS1);
  apply1_kernel<<<BN / 4, 256, 0, stream>>>(VMM1, SS1, Wg, bg, AB1, GATE);

  // ----- pooling + final -----
  softmax_kernel<<<NBATCH, 256, 0, stream>>>(GATE, ALPHA);
  gemm_fp_kernel<<<(BN / 64) * 2, 256, 0, stream>>>(AB1, WFK, bf, ALPHA, POOLED);
  final_kernel<<<NBATCH, 256, 0, stream>>>(POOLED, Wl, bl, out);
}

// Round 10
// 410.545 us; speedup vs baseline: 1.3100x; 1.0163x over previous
//
#include <hip/hip_runtime.h>
#include <hip/hip_bf16.h>
#include <math.h>

// ---------------- problem constants ----------------
static constexpr int NBATCH = 4;
static constexpr int NPTS   = 4096;
static constexpr int BN     = NBATCH * NPTS;   // 16384
static constexpr int KNN    = 20;
static constexpr float BN_EPS = 1e-5f;
static constexpr float SLOPE  = 0.2f;
static constexpr int DF = 512, DOUT = 256;

#define FINF __builtin_huge_valf()

typedef short bf16x8 __attribute__((ext_vector_type(8)));
typedef float f32x4  __attribute__((ext_vector_type(4)));

// ---------------- workspace layout (bytes) ----------------
static constexpr size_t OFF_H0     = 0;                    // 4 MB: VMM0
static constexpr size_t OFF_IDX0   = 4194304;
static constexpr size_t OFF_IDX1   = 5505024;
static constexpr size_t OFF_D2     = 6815744;
static constexpr size_t OFF_GATE   = 6881280;
static constexpr size_t OFF_ALPHA  = 6946816;
static constexpr size_t OFF_STATS0 = 7014912;
static constexpr size_t OFF_STATS1 = 7015424;
static constexpr size_t OFF_POOLED = 7017472;              // -> 7,025,664
static constexpr size_t ZERO_OFF   = OFF_STATS0;
static constexpr size_t ZERO_BYTES = 7025664 - 7014912;
static constexpr size_t OFF_P1     = 7025664;              // 8 MB bf16 (gemm_pq1 out)
static constexpr size_t OFF_PDU    = OFF_P1;               // S=4: 5.24 MB (dead before P1)
static constexpr size_t OFF_WQK    = 23802880;             // 128 KB  [16][512][8] bf16
static constexpr size_t OFF_WFK    = 23933952;             // 512 KB  [64][512][8] bf16
static constexpr size_t OFF_Q1     = 27997184;             // 8 MB bf16
static constexpr size_t OFF_U0     = OFF_Q1;               // 1 MB (dead before P0)
static constexpr size_t OFF_V0     = OFF_Q1 + 1048576;     // 1 MB
static constexpr size_t OFF_P0     = OFF_Q1;               // 2 MB bf16
static constexpr size_t OFF_Q0     = OFF_Q1 + 2097152;     // 2 MB bf16
static constexpr size_t OFF_H1     = 44774400;             // 16 MB: VMM1 then AB1 (in place)
static constexpr size_t OFF_AB     = 61551616;             // 4 MB -> 65,745,920

// ---------------- helpers ----------------
__device__ inline unsigned short f2bf_rne(float x) {
  unsigned int u = __float_as_uint(x);
  unsigned int lsb = (u >> 16) & 1u;
  u += 0x7fffu + lsb;
  return (unsigned short)(u >> 16);
}
__device__ inline float bf2f(unsigned short s) {
  return __uint_as_float((unsigned int)s << 16);
}
__device__ inline unsigned umn(unsigned a, unsigned b) { return a < b ? a : b; }
// clamp(v,lo,hi), lo<=hi == sorted-insert slot update; identity when v>=hi.
// asm v_med3_u32: PROVEN fastest form (R7/R8/R9 A/B).
__device__ inline unsigned umed3(unsigned v, unsigned lo, unsigned hi) {
  unsigned d;
  asm("v_med3_u32 %0, %1, %2, %3" : "=v"(d) : "v"(v), "v"(lo), "v"(hi));
  return d;
}

// ---------------- prep0: d2(x) + layer-0 split packing, fused ----------------
// U=[A,B,A,B,0..] (queries), V=[A,A,B,B,0..] (cands):
// dot(U_q,V_c) = Aq.Ac + Bq.Ac + Aq.Bc + Bq.Bc  (exact 4-product)
__global__ __launch_bounds__(256) void prep0_kernel(
    const float* __restrict__ x, float* __restrict__ d2,
    unsigned short* __restrict__ U0, unsigned short* __restrict__ V0) {
  int n = blockIdx.x * 256 + threadIdx.x;
  float v0 = x[(size_t)n * 3], v1 = x[(size_t)n * 3 + 1], v2 = x[(size_t)n * 3 + 2];
  d2[n] = v0 * v0 + v1 * v1 + v2 * v2;
  unsigned short A0 = f2bf_rne(v0), A1 = f2bf_rne(v1), A2 = f2bf_rne(v2);
  unsigned short B0 = f2bf_rne(v0 - bf2f(A0));
  unsigned short B1 = f2bf_rne(v1 - bf2f(A1));
  unsigned short B2 = f2bf_rne(v2 - bf2f(A2));
  ushort4 z = make_ushort4(0, 0, 0, 0);
  unsigned short* up = U0 + ((size_t)n << 5);
  ((ushort4*)up)[0] = make_ushort4(A0, A1, A2, B0);
  ((ushort4*)up)[1] = make_ushort4(B1, B2, A0, A1);
  ((ushort4*)up)[2] = make_ushort4(A2, B0, B1, B2);
  ((ushort4*)up)[3] = z; ((ushort4*)up)[4] = z; ((ushort4*)up)[5] = z;
  ((ushort4*)up)[6] = z; ((ushort4*)up)[7] = z;
  unsigned short* vp = V0 + ((size_t)n << 5);
  ((ushort4*)vp)[0] = make_ushort4(A0, A1, A2, A0);
  ((ushort4*)vp)[1] = make_ushort4(A1, A2, B0, B1);
  ((ushort4*)vp)[2] = make_ushort4(B2, B0, B1, B2);
  ((ushort4*)vp)[3] = z; ((ushort4*)vp)[4] = z; ((ushort4*)vp)[5] = z;
  ((ushort4*)vp)[6] = z; ((ushort4*)vp)[7] = z;
}

// ---------------- fused weight prep: WQK [16][512][8] + WFK [64][512][8] ------
// K-chunk-major layout -> gemm B-loads are 256B-contiguous per 16-lane group.
__global__ __launch_bounds__(256) void wprep_kernel(
    const float* __restrict__ Wt, const float* __restrict__ Wp,
    const float* __restrict__ Wf,
    unsigned short* __restrict__ wqk, unsigned short* __restrict__ wfk) {
  int bid = blockIdx.x;
  if (bid < 128) {           // WQK: 512 cols x 64 k
    int t = bid * 256 + threadIdx.x;
    int o = t >> 6, k = t & 63;
    float w;
    if (o < 256) w = Wt[(size_t)k * 256 + o];
    else { int oo = o - 256; w = Wp[(size_t)k * 256 + oo] - Wt[(size_t)k * 256 + oo]; }
    unsigned short a = f2bf_rne(w);
    unsigned short b = f2bf_rne(w - bf2f(a));
    wqk[((size_t)(k >> 3) * 512 + o) * 8 + (k & 7)]          = a;   // A at k
    wqk[((size_t)((k + 64) >> 3) * 512 + o) * 8 + (k & 7)]   = b;   // B at k+64
  } else {                   // WFK: 512 cols x 256 k
    int t = (bid - 128) * 256 + threadIdx.x;
    int o = t >> 8, k = t & 255;
    float w = Wf[(size_t)k * 512 + o];
    unsigned short a = f2bf_rne(w);
    unsigned short b = f2bf_rne(w - bf2f(a));
    wfk[((size_t)(k >> 3) * 512 + o) * 8 + (k & 7)]          = a;   // A at k
    wfk[((size_t)((k + 256) >> 3) * 512 + o) * 8 + (k & 7)]  = b;   // B at k+256
  }
}

// ---------------- unified MFMA KNN with in-register med3 selection ----------------
// KW=128: LDS rows of 128 shorts with 16B-block XOR swizzle (block s of row r
// stored at s^(r&7)) -> conflict-free b128 on both write and read sides.
template<int KW, int CST, int S>
__global__ __launch_bounds__(256, 4) void knn_mfsel_kernel(
    const unsigned short* __restrict__ cab,
    const unsigned short* __restrict__ qab,
    const float* __restrict__ d2,
    unsigned* __restrict__ pdu) {
  constexpr int CS = NPTS / S, NCH = CS / 32;
  __shared__ __align__(16) unsigned short cbuf[2][32 * CST];
  __shared__ __align__(16) float cd2b[2][32];

  int bid = blockIdx.x;
  int s   = bid & (S - 1);
  int qb  = bid / S;
  int b   = qb >> 6;
  int qloc = (qb & 63) * 64;
  int wv = threadIdx.x >> 6, lane = threadIdx.x & 63;
  int l15 = lane & 15, lg = lane >> 4;
  int qg = b * NPTS + qloc + wv * 16 + l15;

  bf16x8 af[KW / 32];
#pragma unroll
  for (int kk = 0; kk < KW / 32; ++kk)
    af[kk] = *(const bf16x8*)(qab + (size_t)qg * KW + kk * 32 + lg * 8);
  float d2q = d2[qg];

  unsigned bd[KNN];
#pragma unroll
  for (int k = 0; k < KNN; ++k) bd[k] = 0xFFFFFFFFu;

  int scand = threadIdx.x >> 3, sseg = threadIdx.x & 7;
  const unsigned short* sbase = cab + ((size_t)(b * NPTS + s * CS)) * KW;
  const float* d2base = d2 + b * NPTS + s * CS;

  bf16x8 r0, r1;
  ushort4 r2;
  float rd2 = 0.f;

  if constexpr (KW == 128) {
    const unsigned short* src = sbase + (size_t)scand * KW + sseg * 16;
    r0 = *(const bf16x8*)src;
    r1 = *(const bf16x8*)(src + 8);
    int s0 = (2 * sseg) ^ (scand & 7), s1 = (2 * sseg + 1) ^ (scand & 7);
    *(bf16x8*)&cbuf[0][scand * 128 + s0 * 8] = r0;
    *(bf16x8*)&cbuf[0][scand * 128 + s1 * 8] = r1;
  } else {
    r2 = *(const ushort4*)(sbase + (size_t)scand * KW + sseg * 4);
    *(ushort4*)&cbuf[0][scand * CST + sseg * 4] = r2;
  }
  if (threadIdx.x < 32) cd2b[0][threadIdx.x] = d2base[threadIdx.x];
  __syncthreads();

#pragma unroll 1
  for (int ch = 0; ch < NCH; ++ch) {
    int cur = ch & 1;
    if (ch < NCH - 1) {
      if constexpr (KW == 128) {
        const unsigned short* src = sbase + (size_t)(32 * (ch + 1) + scand) * KW + sseg * 16;
        r0 = *(const bf16x8*)src;
        r1 = *(const bf16x8*)(src + 8);
      } else {
        r2 = *(const ushort4*)(sbase + (size_t)(32 * (ch + 1) + scand) * KW + sseg * 4);
      }
      if (threadIdx.x < 32) rd2 = d2base[32 * (ch + 1) + threadIdx.x];
    }

    f32x4 acc0 = (f32x4){0.f, 0.f, 0.f, 0.f};
    f32x4 acc1 = (f32x4){0.f, 0.f, 0.f, 0.f};
    if constexpr (KW == 128) {
      // each cbuf b128 word feeds BOTH split pairings -> 8 swizzled ds_read_b128
#pragma unroll
      for (int j = 0; j < 4; ++j) {
        int blk = (4 * j + lg) ^ (l15 & 7);
        bf16x8 a0 = *(const bf16x8*)&cbuf[cur][l15 * 128 + blk * 8];
        bf16x8 a1 = *(const bf16x8*)&cbuf[cur][(16 + l15) * 128 + blk * 8];
        acc0 = __builtin_amdgcn_mfma_f32_16x16x32_bf16(a0, af[j], acc0, 0, 0, 0);
        acc0 = __builtin_amdgcn_mfma_f32_16x16x32_bf16(a0, af[(j + 2) & 3], acc0, 0, 0, 0);
        acc1 = __builtin_amdgcn_mfma_f32_16x16x32_bf16(a1, af[j], acc1, 0, 0, 0);
        acc1 = __builtin_amdgcn_mfma_f32_16x16x32_bf16(a1, af[(j + 2) & 3], acc1, 0, 0, 0);
      }
    } else {
      bf16x8 a0 = *(const bf16x8*)&cbuf[cur][l15 * CST + lg * 8];
      bf16x8 a1 = *(const bf16x8*)&cbuf[cur][(16 + l15) * CST + lg * 8];
      acc0 = __builtin_amdgcn_mfma_f32_16x16x32_bf16(a0, af[0], acc0, 0, 0, 0);
      acc1 = __builtin_amdgcn_mfma_f32_16x16x32_bf16(a1, af[0], acc1, 0, 0, 0);
    }

    int cb = s * CS + ch * 32;
#pragma unroll
    for (int t = 0; t < 2; ++t) {
      f32x4 cd4 = *(const f32x4*)&cd2b[cur][t * 16 + lg * 4];
      f32x4 ac = t ? acc1 : acc0;
#pragma unroll
      for (int r = 0; r < 4; ++r) {
        float dist = fmaxf(fmaf(-2.f, ac[r], d2q + cd4[r]), 0.f);
        unsigned key = (__float_as_uint(dist) & 0xFFFFF000u)
                     | (unsigned)(cb + t * 16 + lg * 4 + r);
        // unconditional sorted-insert: identity when key >= bd[19]
#pragma unroll
        for (int t_ = KNN - 1; t_ >= 1; --t_) bd[t_] = umed3(key, bd[t_ - 1], bd[t_]);
        bd[0] = umn(bd[0], key);
      }
    }

    if (ch < NCH - 1) {
      if constexpr (KW == 128) {
        int s0 = (2 * sseg) ^ (scand & 7), s1 = (2 * sseg + 1) ^ (scand & 7);
        *(bf16x8*)&cbuf[cur ^ 1][scand * 128 + s0 * 8] = r0;
        *(bf16x8*)&cbuf[cur ^ 1][scand * 128 + s1 * 8] = r1;
      } else {
        *(ushort4*)&cbuf[cur ^ 1][scand * CST + sseg * 4] = r2;
      }
      if (threadIdx.x < 32) cd2b[cur ^ 1][threadIdx.x] = rd2;
    }
    __syncthreads();
  }

  // merge 4 per-lane sorted lists via shuffles into lg==0 lanes (exact union)
#pragma unroll 1
  for (int li = 1; li < 4; ++li) {
#pragma unroll 1
    for (int k = 0; k < KNN; ++k) {
      unsigned v = __shfl(bd[k], l15 + li * 16, 64);
      if (lg == 0 && v < bd[KNN - 1]) {
#pragma unroll
        for (int t_ = KNN - 1; t_ >= 1; --t_) bd[t_] = umed3(v, bd[t_ - 1], bd[t_]);
        bd[0] = umn(bd[0], v);
      }
    }
  }
  if (lg == 0) {
    unsigned* dst = pdu + ((size_t)(b * NPTS + qloc + wv * 16 + l15) * S + s) * KNN;
#pragma unroll
    for (int k = 0; k < KNN; ++k) dst[k] = bd[k];
  }
}

// ---------------- merge S sorted packed-key lists -> idx ----------------
template<int S>
__global__ __launch_bounds__(256) void knn_mergek_kernel(
    const unsigned* __restrict__ pdu, int* __restrict__ idx) {
  int n = blockIdx.x * 256 + threadIdx.x;
  const unsigned* l0 = pdu + (size_t)n * S * KNN;
  unsigned bd[KNN];
#pragma unroll
  for (int k = 0; k < KNN; ++k) bd[k] = l0[k];
#pragma unroll 1
  for (int s = 1; s < S; ++s) {
#pragma unroll 1
    for (int k = 0; k < KNN; ++k) {
      unsigned v = l0[s * KNN + k];
      if (!(v < bd[KNN - 1])) break;
#pragma unroll
      for (int t_ = KNN - 1; t_ >= 1; --t_) bd[t_] = umed3(v, bd[t_ - 1], bd[t_]);
      bd[0] = umn(bd[0], v);
    }
  }
#pragma unroll
  for (int k = 0; k < KNN; ++k) idx[(size_t)n * KNN + k] = (int)(bd[k] & 0xFFFu);
}

// ---------------- EdgeConv0: P,Q projections (D=3), bf16 outputs ----------------
__global__ __launch_bounds__(256) void pq0_kernel(
    const float* __restrict__ x,
    const float* __restrict__ Wt, const float* __restrict__ bt,
    const float* __restrict__ Wp, const float* __restrict__ bp,
    unsigned short* __restrict__ P0, unsigned short* __restrict__ Q0) {
  int t = blockIdx.x * 256 + threadIdx.x;
  int c = t & 63, n = t >> 6;
  const float* xr = x + (size_t)n * 3;
  float x0 = xr[0], x1 = xr[1], x2 = xr[2];
  float wt0 = Wt[0 * 64 + c], wt1 = Wt[1 * 64 + c], wt2 = Wt[2 * 64 + c];
  float wp0 = Wp[0 * 64 + c], wp1 = Wp[1 * 64 + c], wp2 = Wp[2 * 64 + c];
  P0[t] = f2bf_rne(x0 * wt0 + x1 * wt1 + x2 * wt2 + bt[c] + bp[c]);
  Q0[t] = f2bf_rne(x0 * (wp0 - wt0) + x1 * (wp1 - wt1) + x2 * (wp2 - wt2));
}

// ---------------- fused BN gather (bf16 P,Q): stats + per-(n,c) bf16 vmax/vmin ----
template<int C, int PB>
__global__ __launch_bounds__(256) void bn_gather_kernel(
    const unsigned short* __restrict__ P, const unsigned short* __restrict__ Q,
    const int* __restrict__ idx, float* __restrict__ stats,
    unsigned* __restrict__ vmm) {
  constexpr int G = 256 / C;
  int c = threadIdx.x % C;
  int g = threadIdx.x / C;
  int p0 = blockIdx.x * PB;
  float sum = 0.f, sq = 0.f;
  for (int p = g; p < PB; p += G) {
    int n = p0 + p;
    int b = n >> 12;
    float pc = bf2f(P[(size_t)n * C + c]);
    const int* id = idx + (size_t)n * KNN;
    float vmax = -FINF, vmin = FINF;
#pragma unroll
    for (int k = 0; k < KNN; ++k) {
      int j = id[k];
      float v = pc + bf2f(Q[((size_t)(b << 12) + j) * C + c]);
      sum += v; sq += v * v;
      vmax = fmaxf(vmax, v); vmin = fminf(vmin, v);
    }
    vmm[(size_t)n * C + c] = ((unsigned)f2bf_rne(vmax) << 16) | f2bf_rne(vmin);
  }
  if constexpr (G > 1) {
    __shared__ float ls[2][256];
    ls[0][threadIdx.x] = sum; ls[1][threadIdx.x] = sq;
    __syncthreads();
    if (g == 0) {
#pragma unroll
      for (int gg = 1; gg < G; ++gg) { sum += ls[0][gg * C + c]; sq += ls[1][gg * C + c]; }
      atomicAdd(&stats[c], sum); atomicAdd(&stats[C + c], sq);
    }
  } else {
    atomicAdd(&stats[c], sum); atomicAdd(&stats[C + c], sq);
  }
}

// ---------------- apply0 (folds bn_final0): vmm0 -> AB split + D2 ----------------
__global__ __launch_bounds__(256) void apply0_kernel(
    const unsigned* __restrict__ vmm, const float* __restrict__ stats,
    const float* __restrict__ gamma, const float* __restrict__ beta,
    unsigned short* __restrict__ ab, float* __restrict__ d2) {
  __shared__ float ssl[128];
  if (threadIdx.x < 64) {
    int c = threadIdx.x;
    const float cnt = (float)((size_t)BN * KNN);
    float mu  = stats[c] / cnt;
    float var = stats[64 + c] / cnt - mu * mu;
    float sc  = gamma[c] * rsqrtf(var + BN_EPS);
    ssl[c] = sc;
    ssl[64 + c] = beta[c] - mu * sc;
  }
  __syncthreads();
  int wv = threadIdx.x >> 6, lane = threadIdx.x & 63;
  int n = blockIdx.x * 4 + wv;
  unsigned pk = vmm[(size_t)n * 64 + lane];
  float sc = ssl[lane], sh = ssl[64 + lane];
  float vmax = bf2f((unsigned short)(pk >> 16));
  float vmin = bf2f((unsigned short)(pk & 0xFFFFu));
  float m = (sc >= 0.f) ? vmax : vmin;
  float y = fmaf(m, sc, sh);
  y = (y >= 0.f) ? y : SLOPE * y;
  unsigned short a = f2bf_rne(y);
  unsigned short b = f2bf_rne(y - bf2f(a));
  ab[(size_t)n * 128 + lane] = a;
  ab[(size_t)n * 128 + 64 + lane] = b;
  float s = y * y;
#pragma unroll
  for (int off = 32; off >= 1; off >>= 1) s += __shfl_down(s, off);
  if (lane == 0) d2[n] = s;
}

// ---------------- gemm_pq1: [BN,128sp]@[128sp,512] -> bf16 P1|Q1, bias fused ----
// As: swizzled LDS rows of 128 shorts; W loads coalesced via [16][512][8] layout.
__global__ __launch_bounds__(256, 2) void gemm_pq1_kernel(
    const unsigned short* __restrict__ ab, const unsigned short* __restrict__ wqk,
    const float* __restrict__ bt, const float* __restrict__ bp,
    unsigned short* __restrict__ P1, unsigned short* __restrict__ Q1) {
  __shared__ __align__(16) unsigned short As[64 * 128];
  int cb = blockIdx.x & 1;
  int rb = blockIdx.x >> 1;
  int wv = threadIdx.x >> 6, lane = threadIdx.x & 63;
  int l15 = lane & 15, lg = lane >> 4;
  {
    int row = threadIdx.x >> 2, seg = threadIdx.x & 3;
    const unsigned short* src = ab + ((size_t)(rb * 64 + row)) * 128 + seg * 32;
#pragma unroll
    for (int u = 0; u < 4; ++u) {
      int blk = (seg * 4 + u) ^ (row & 7);
      *(bf16x8*)&As[row * 128 + blk * 8] = *(const bf16x8*)(src + u * 8);
    }
  }
  __syncthreads();
  int wcol = cb * 256 + wv * 64;
  f32x4 acc[4][4];
#pragma unroll
  for (int m = 0; m < 4; ++m)
#pragma unroll
    for (int n = 0; n < 4; ++n) acc[m][n] = (f32x4){0.f, 0.f, 0.f, 0.f};
#pragma unroll
  for (int kk = 0; kk < 4; ++kk) {
    int k8a = kk * 4 + lg;
    int k8b = ((kk + 2) & 3) * 4 + lg;
    bf16x8 am[4], b0[4], b1[4];
#pragma unroll
    for (int m = 0; m < 4; ++m) {
      int row = m * 16 + l15;
      am[m] = *(const bf16x8*)&As[row * 128 + (k8a ^ (l15 & 7)) * 8];
    }
#pragma unroll
    for (int n = 0; n < 4; ++n) {
      int col = wcol + n * 16 + l15;
      b0[n] = *(const bf16x8*)(wqk + ((size_t)k8a * 512 + col) * 8);
      b1[n] = *(const bf16x8*)(wqk + ((size_t)k8b * 512 + col) * 8);
    }
#pragma unroll
    for (int m = 0; m < 4; ++m)
#pragma unroll
      for (int n = 0; n < 4; ++n) {
        acc[m][n] = __builtin_amdgcn_mfma_f32_16x16x32_bf16(am[m], b0[n], acc[m][n], 0, 0, 0);
        acc[m][n] = __builtin_amdgcn_mfma_f32_16x16x32_bf16(am[m], b1[n], acc[m][n], 0, 0, 0);
      }
  }
#pragma unroll
  for (int n = 0; n < 4; ++n) {
    int col = wcol + n * 16 + l15;
    bool isP = col < 256;
    float bias = isP ? (bt[col] + bp[col]) : 0.f;
    unsigned short* dst = isP ? (P1 + col) : (Q1 + (col - 256));
#pragma unroll
    for (int m = 0; m < 4; ++m)
#pragma unroll
      for (int r = 0; r < 4; ++r) {
        int row = rb * 64 + m * 16 + lg * 4 + r;
        dst[(size_t)row * 256] = f2bf_rne(acc[m][n][r] + bias);
      }
  }
}

// ---------------- apply1 (folds bn_final1): vmm1 -> AB1 (in place) + gate ------
__global__ __launch_bounds__(256) void apply1_kernel(
    const unsigned* __restrict__ vmm, const float* __restrict__ stats,
    const float* __restrict__ gamma, const float* __restrict__ beta,
    const float* __restrict__ Wg, const float* __restrict__ bg,
    unsigned short* __restrict__ ab1, float* __restrict__ gate) {
  __shared__ float ssl[512];
  {
    int c = threadIdx.x;
    const float cnt = (float)((size_t)BN * KNN);
    float mu  = stats[c] / cnt;
    float var = stats[256 + c] / cnt - mu * mu;
    float sc  = gamma[c] * rsqrtf(var + BN_EPS);
    ssl[c] = sc;
    ssl[256 + c] = beta[c] - mu * sc;
  }
  __syncthreads();
  int wv = threadIdx.x >> 6, lane = threadIdx.x & 63;
  int n = blockIdx.x * 4 + wv;
  unsigned pk[4];
#pragma unroll
  for (int i = 0; i < 4; ++i) pk[i] = vmm[(size_t)n * 256 + lane + 64 * i];  // reads first
  float gsum = 0.f;
  unsigned short Aa[4], Bb[4];
#pragma unroll
  for (int i = 0; i < 4; ++i) {
    int c = lane + 64 * i;
    float sc = ssl[c], sh = ssl[256 + c];
    float vmax = bf2f((unsigned short)(pk[i] >> 16));
    float vmin = bf2f((unsigned short)(pk[i] & 0xFFFFu));
    float m = (sc >= 0.f) ? vmax : vmin;
    float y = fmaf(m, sc, sh);
    y = (y >= 0.f) ? y : SLOPE * y;
    Aa[i] = f2bf_rne(y);
    Bb[i] = f2bf_rne(y - bf2f(Aa[i]));
    gsum += y * Wg[c];
  }
#pragma unroll
  for (int i = 0; i < 4; ++i) {
    ab1[(size_t)n * 512 + lane + 64 * i]       = Aa[i];
    ab1[(size_t)n * 512 + 256 + lane + 64 * i] = Bb[i];
  }
#pragma unroll
  for (int off = 32; off >= 1; off >>= 1) gsum += __shfl_down(gsum, off);
  if (lane == 0) gate[n] = fmaxf(gsum + bg[0], 0.f);
}

// ---------------- softmax over N per batch ----------------
__global__ void softmax_kernel(const float* __restrict__ gate,
                               float* __restrict__ alpha) {
  __shared__ float red[256];
  int b = blockIdx.x;
  const float* g = gate + (size_t)b * NPTS;
  float* a = alpha + (size_t)b * NPTS;
  float m = -FINF;
  for (int i = threadIdx.x; i < NPTS; i += 256) m = fmaxf(m, g[i]);
  red[threadIdx.x] = m; __syncthreads();
  for (int st = 128; st >= 1; st >>= 1) {
    if (threadIdx.x < st) red[threadIdx.x] = fmaxf(red[threadIdx.x], red[threadIdx.x + st]);
    __syncthreads();
  }
  m = red[0]; __syncthreads();
  float s = 0.f;
  for (int i = threadIdx.x; i < NPTS; i += 256) s += expf(g[i] - m);
  red[threadIdx.x] = s; __syncthreads();
  for (int st = 128; st >= 1; st >>= 1) {
    if (threadIdx.x < st) red[threadIdx.x] += red[threadIdx.x + st];
    __syncthreads();
  }
  float inv = 1.f / red[0];
  for (int i = threadIdx.x; i < NPTS; i += 256) a[i] = expf(g[i] - m) * inv;
}

// ---------------- gemm_fp: feat GEMM (split, K=512) + relu + alpha-pool ----------
// As swizzled; W loads coalesced via [64][512][8] layout.
__global__ __launch_bounds__(256, 2) void gemm_fp_kernel(
    const unsigned short* __restrict__ ab1, const unsigned short* __restrict__ wfk,
    const float* __restrict__ bf, const float* __restrict__ alpha,
    float* __restrict__ pooled) {
  __shared__ __align__(16) unsigned short As[2][64 * 128];
  int cb = blockIdx.x & 1;
  int rb = blockIdx.x >> 1;
  int wv = threadIdx.x >> 6, lane = threadIdx.x & 63;
  int l15 = lane & 15, lg = lane >> 4;
  int wcol = cb * 256 + wv * 64;
  int rowbase = rb * 64;
  f32x4 acc[4][4];
#pragma unroll
  for (int m = 0; m < 4; ++m)
#pragma unroll
    for (int n = 0; n < 4; ++n) acc[m][n] = (f32x4){0.f, 0.f, 0.f, 0.f};

#pragma unroll 1
  for (int kc = 0; kc < 2; ++kc) {
    __syncthreads();
    {
      int row = threadIdx.x >> 2, seg = threadIdx.x & 3;
      const unsigned short* s0 = ab1 + ((size_t)(rowbase + row)) * 512 + kc * 128 + seg * 32;
      const unsigned short* s1 = s0 + 256;
#pragma unroll
      for (int u = 0; u < 4; ++u) {
        int blk = (seg * 4 + u) ^ (row & 7);
        *(bf16x8*)&As[0][row * 128 + blk * 8] = *(const bf16x8*)(s0 + u * 8);
        *(bf16x8*)&As[1][row * 128 + blk * 8] = *(const bf16x8*)(s1 + u * 8);
      }
    }
    __syncthreads();
#pragma unroll
    for (int h = 0; h < 2; ++h) {
#pragma unroll
      for (int kk = 0; kk < 4; ++kk) {
        int s  = kc * 4 + h * 8 + kk;      // absolute 32-slice 0..15
        int sp = (s + 8) & 15;
        bf16x8 am[4], b0[4], b1[4];
#pragma unroll
        for (int m = 0; m < 4; ++m) {
          int row = m * 16 + l15;
          am[m] = *(const bf16x8*)&As[h][row * 128 + ((kk * 4 + lg) ^ (l15 & 7)) * 8];
        }
#pragma unroll
        for (int n = 0; n < 4; ++n) {
          int col = wcol + n * 16 + l15;
          b0[n] = *(const bf16x8*)(wfk + ((size_t)(s * 4 + lg) * 512 + col) * 8);
          b1[n] = *(const bf16x8*)(wfk + ((size_t)(sp * 4 + lg) * 512 + col) * 8);
        }
#pragma unroll
        for (int m = 0; m < 4; ++m)
#pragma unroll
          for (int n = 0; n < 4; ++n) {
            acc[m][n] = __builtin_amdgcn_mfma_f32_16x16x32_bf16(am[m], b0[n], acc[m][n], 0, 0, 0);
            acc[m][n] = __builtin_amdgcn_mfma_f32_16x16x32_bf16(am[m], b1[n], acc[m][n], 0, 0, 0);
          }
      }
    }
  }
  int b = rowbase >> 12;
  float al[4][4];
#pragma unroll
  for (int m = 0; m < 4; ++m)
#pragma unroll
    for (int r = 0; r < 4; ++r)
      al[m][r] = alpha[rowbase + m * 16 + lg * 4 + r];
#pragma unroll
  for (int n = 0; n < 4; ++n) {
    int col = wcol + n * 16 + l15;
    float bv = bf[col];
    float po = 0.f;
#pragma unroll
    for (int m = 0; m < 4; ++m)
#pragma unroll
      for (int r = 0; r < 4; ++r)
        po += al[m][r] * fmaxf(acc[m][n][r] + bv, 0.f);
    po += __shfl_xor(po, 16, 64);
    po += __shfl_xor(po, 32, 64);
    if (lg == 0) atomicAdd(&pooled[(size_t)b * DF + col], po);
  }
}

// ---------------- out = pooled @ Wl + bl ----------------
__global__ __launch_bounds__(256) void final_kernel(
    const float* __restrict__ pooled, const float* __restrict__ Wl,
    const float* __restrict__ bl, float* __restrict__ out) {
  __shared__ float ps[DF];
  int b = blockIdx.x, j = threadIdx.x;
  for (int e = threadIdx.x; e < DF; e += 256) ps[e] = pooled[(size_t)b * DF + e];
  __syncthreads();
  float a0 = 0.f, a1 = 0.f, a2 = 0.f, a3 = 0.f;
  for (int o = 0; o < DF; o += 4) {
    a0 += ps[o + 0] * Wl[(size_t)(o + 0) * DOUT + j];
    a1 += ps[o + 1] * Wl[(size_t)(o + 1) * DOUT + j];
    a2 += ps[o + 2] * Wl[(size_t)(o + 2) * DOUT + j];
    a3 += ps[o + 3] * Wl[(size_t)(o + 3) * DOUT + j];
  }
  out[(size_t)b * DOUT + j] = (a0 + a1) + (a2 + a3) + bl[j];
}

// ---------------- launch ----------------
extern "C" void kernel_launch(void* const* d_in, const int* in_sizes, int n_in,
                              void* d_out, int out_size, void* d_ws, size_t ws_size,
                              hipStream_t stream) {
  (void)in_sizes; (void)n_in; (void)out_size; (void)ws_size;
  const float* x   = (const float*)d_in[0];
  const float* Wt0 = (const float*)d_in[1];
  const float* bt0 = (const float*)d_in[2];
  const float* Wp0 = (const float*)d_in[3];
  const float* bp0 = (const float*)d_in[4];
  const float* g0  = (const float*)d_in[5];
  const float* be0 = (const float*)d_in[6];
  const float* Wt1 = (const float*)d_in[7];
  const float* bt1 = (const float*)d_in[8];
  const float* Wp1 = (const float*)d_in[9];
  const float* bp1 = (const float*)d_in[10];
  const float* g1  = (const float*)d_in[11];
  const float* be1 = (const float*)d_in[12];
  const float* Wg  = (const float*)d_in[13];
  const float* bg  = (const float*)d_in[14];
  const float* Wf  = (const float*)d_in[15];
  const float* bf  = (const float*)d_in[16];
  const float* Wl  = (const float*)d_in[17];
  const float* bl  = (const float*)d_in[18];
  float* out = (float*)d_out;
  char* ws = (char*)d_ws;

  unsigned* VMM0 = (unsigned*)(ws + OFF_H0);
  int*   IDX0   = (int*)  (ws + OFF_IDX0);
  int*   IDX1   = (int*)  (ws + OFF_IDX1);
  float* D2     = (float*)(ws + OFF_D2);
  float* GATE   = (float*)(ws + OFF_GATE);
  float* ALPHA  = (float*)(ws + OFF_ALPHA);
  float* STATS0 = (float*)(ws + OFF_STATS0);
  float* STATS1 = (float*)(ws + OFF_STATS1);
  float* POOLED = (float*)(ws + OFF_POOLED);
  unsigned short* P1 = (unsigned short*)(ws + OFF_P1);
  unsigned short* Q1 = (unsigned short*)(ws + OFF_Q1);
  unsigned* VMM1 = (unsigned*)(ws + OFF_H1);
  unsigned short* AB1 = (unsigned short*)(ws + OFF_H1);   // in place over VMM1
  unsigned short* P0 = (unsigned short*)(ws + OFF_P0);
  unsigned short* Q0 = (unsigned short*)(ws + OFF_Q0);
  unsigned short* AB = (unsigned short*)(ws + OFF_AB);
  unsigned* PDU = (unsigned*)(ws + OFF_PDU);
  unsigned short* U0 = (unsigned short*)(ws + OFF_U0);
  unsigned short* V0 = (unsigned short*)(ws + OFF_V0);
  unsigned short* WQK = (unsigned short*)(ws + OFF_WQK);
  unsigned short* WFK = (unsigned short*)(ws + OFF_WFK);

  hipMemsetAsync(ws + ZERO_OFF, 0, ZERO_BYTES, stream);

  wprep_kernel<<<128 + 512, 256, 0, stream>>>(Wt1, Wp1, Wf, WQK, WFK);

  // ----- layer 0 -----
  prep0_kernel<<<BN / 256, 256, 0, stream>>>(x, D2, U0, V0);
  knn_mfsel_kernel<32, 40, 4><<<(BN / 64) * 4, 256, 0, stream>>>(V0, U0, D2, PDU);
  knn_mergek_kernel<4><<<BN / 256, 256, 0, stream>>>(PDU, IDX0);
  pq0_kernel<<<BN * 64 / 256, 256, 0, stream>>>(x, Wt0, bt0, Wp0, bp0, P0, Q0);
  bn_gather_kernel<64, 32><<<BN / 32, 256, 0, stream>>>(P0, Q0, IDX0, STATS0, VMM0);
  apply0_kernel<<<BN / 4, 256, 0, stream>>>(VMM0, STATS0, g0, be0, AB, D2);

  // ----- layer 1 -----
  knn_mfsel_kernel<128, 128, 4><<<(BN / 64) * 4, 256, 0, stream>>>(AB, AB, D2, PDU);
  knn_mergek_kernel<4><<<BN / 256, 256, 0, stream>>>(PDU, IDX1);
  gemm_pq1_kernel<<<(BN / 64) * 2, 256, 0, stream>>>(AB, WQK, bt1, bp1, P1, Q1);
  bn_gather_kernel<256, 16><<<BN / 16, 256, 0, stream>>>(P1, Q1, IDX1, STATS1, VMM1);
  apply1_kernel<<<BN / 4, 256, 0, stream>>>(VMM1, STATS1, g1, be1, Wg, bg, AB1, GATE);

  // ----- pooling + final -----
  softmax_kernel<<<NBATCH, 256, 0, stream>>>(GATE, ALPHA);
  gemm_fp_kernel<<<(BN / 64) * 2, 256, 0, stream>>>(AB1, WFK, bf, ALPHA, POOLED);
  final_kernel<<<NBATCH, 256, 0, stream>>>(POOLED, Wl, bl, out);
}